// Round 1
// baseline (827.817 us; speedup 1.0000x reference)
//
#include <hip/hip_runtime.h>

#define B_ 32
#define D_ 512
#define K_ 64
#define N_ 4096

// ---------------------------------------------------------------------------
// Kernel A: scores = W @ X[b] + bias, softmax over K -> P [B][N][K] (n-major)
// One thread per n. 64 f32 accumulators in VGPRs; W via wave-uniform loads.
// ---------------------------------------------------------------------------
__global__ __launch_bounds__(256) void vlad_scores(const float* __restrict__ X,
                                                   const float* __restrict__ W,
                                                   const float* __restrict__ bias,
                                                   float* __restrict__ P) {
    const int b = blockIdx.y;
    const int n = blockIdx.x * 256 + threadIdx.x;
    const float* Xb = X + (size_t)b * D_ * N_;

    float sc[K_];
#pragma unroll
    for (int k = 0; k < K_; ++k) sc[k] = bias[k];

    for (int d = 0; d < D_; d += 4) {
        const float x0 = Xb[(size_t)(d + 0) * N_ + n];
        const float x1 = Xb[(size_t)(d + 1) * N_ + n];
        const float x2 = Xb[(size_t)(d + 2) * N_ + n];
        const float x3 = Xb[(size_t)(d + 3) * N_ + n];
#pragma unroll
        for (int k = 0; k < K_; ++k) {
            // W indices are wave-uniform -> scalar loads through K$
            sc[k] = fmaf(W[k * D_ + d + 0], x0, sc[k]);
            sc[k] = fmaf(W[k * D_ + d + 1], x1, sc[k]);
            sc[k] = fmaf(W[k * D_ + d + 2], x2, sc[k]);
            sc[k] = fmaf(W[k * D_ + d + 3], x3, sc[k]);
        }
    }

    float m = sc[0];
#pragma unroll
    for (int k = 1; k < K_; ++k) m = fmaxf(m, sc[k]);
    float s = 0.f;
#pragma unroll
    for (int k = 0; k < K_; ++k) {
        sc[k] = __expf(sc[k] - m);
        s += sc[k];
    }
    const float inv = 1.f / s;

    float4* Pn = (float4*)(P + ((size_t)b * N_ + n) * K_);
#pragma unroll
    for (int k = 0; k < K_; k += 4) {
        Pn[k >> 2] = make_float4(sc[k] * inv, sc[k + 1] * inv, sc[k + 2] * inv, sc[k + 3] * inv);
    }
}

// ---------------------------------------------------------------------------
// Kernel C: softsum[b][k] = sum_n P[b][n][k]   (block partial + atomicAdd)
// ---------------------------------------------------------------------------
__global__ __launch_bounds__(256) void vlad_softsum(const float* __restrict__ P,
                                                    float* __restrict__ ss) {
    const int b = blockIdx.y;
    const int n0 = blockIdx.x * 256;
    const int k = threadIdx.x & 63;
    const int part = threadIdx.x >> 6;

    float s = 0.f;
    for (int j = 0; j < 64; ++j) {
        const int n = n0 + part + j * 4;
        s += P[((size_t)b * N_ + n) * K_ + k];
    }
    __shared__ float red[4][K_];
    red[part][k] = s;
    __syncthreads();
    if (threadIdx.x < K_) {
        const float t = red[0][k] + red[1][k] + red[2][k] + red[3][k];
        atomicAdd(&ss[b * K_ + k], t);
    }
}

// ---------------------------------------------------------------------------
// Kernel B: agg[b][d][k] += sum_n X[b][d][n] * P[b][n][k]
// Block: 128 threads, tile 128d x 64k, NT=32 n per stage, 8x8 per-thread tile.
// A-tile stored n-major with 16B-chunk XOR swizzle (aligned b128 reads,
// conflict-bounded writes). n-split x8 + f32 global atomics.
// ---------------------------------------------------------------------------
#define NT 32
#define DT 128
__global__ __launch_bounds__(128) void vlad_agg(const float* __restrict__ X,
                                                const float* __restrict__ P,
                                                float* __restrict__ agg) {
    const int b = blockIdx.z;
    const int dt = blockIdx.y;   // 0..3
    const int ns = blockIdx.x;   // 0..7

    __shared__ float ast[NT][DT];       // swizzled: chunk c stored at c ^ (n&7)
    __shared__ float ps[NT][K_ + 4];    // pad to 68 floats

    const int tid = threadIdx.x;
    const int tx = tid & 7;    // k-group: k0 = tx*8
    const int ty = tid >> 3;   // d-group: d0 = ty*8  (0..15)

    float acc[8][8];
#pragma unroll
    for (int i = 0; i < 8; ++i)
#pragma unroll
        for (int j = 0; j < 8; ++j) acc[i][j] = 0.f;

    const float* Xb = X + (size_t)b * D_ * N_ + (size_t)dt * DT * N_;
    const float* Pb = P + (size_t)b * N_ * K_;

    const int nbeg = ns * (N_ / 8);
    for (int n0 = nbeg; n0 < nbeg + (N_ / 8); n0 += NT) {
        // --- stage A tile: 128d x 32n, coalesced global reads, swizzled LDS writes
        {
            const int nn = tid & 31;
            const int dd0 = tid >> 5;   // 0..3
#pragma unroll
            for (int i = 0; i < 32; ++i) {
                const int dd = dd0 + i * 4;
                const float v = Xb[(size_t)dd * N_ + n0 + nn];
                const int c = dd >> 2, r = dd & 3;
                ast[nn][((c ^ (nn & 7)) << 2) + r] = v;
            }
        }
        // --- stage B tile: 32n x 64k, float4 coalesced
        {
#pragma unroll
            for (int i = 0; i < 4; ++i) {
                const int e = (tid + i * 128) * 4;
                const int nn = e >> 6, kk = e & 63;
                const float4 v = *(const float4*)&Pb[(size_t)(n0 + nn) * K_ + kk];
                *(float4*)&ps[nn][kk] = v;
            }
        }
        __syncthreads();

        for (int nn = 0; nn < NT; ++nn) {
            const int sw = nn & 7;
            const float4 a0 = *(const float4*)&ast[nn][(((ty * 2 + 0) ^ sw) << 2)];
            const float4 a1 = *(const float4*)&ast[nn][(((ty * 2 + 1) ^ sw) << 2)];
            const float4 b0 = *(const float4*)&ps[nn][tx * 8];
            const float4 b1 = *(const float4*)&ps[nn][tx * 8 + 4];
            const float a[8] = {a0.x, a0.y, a0.z, a0.w, a1.x, a1.y, a1.z, a1.w};
            const float bv[8] = {b0.x, b0.y, b0.z, b0.w, b1.x, b1.y, b1.z, b1.w};
#pragma unroll
            for (int i = 0; i < 8; ++i)
#pragma unroll
                for (int j = 0; j < 8; ++j) acc[i][j] = fmaf(a[i], bv[j], acc[i][j]);
        }
        __syncthreads();
    }

    const int dbase = dt * DT + ty * 8;
    const int kbase = tx * 8;
#pragma unroll
    for (int i = 0; i < 8; ++i)
#pragma unroll
        for (int j = 0; j < 8; ++j)
            atomicAdd(&agg[((size_t)b * D_ + dbase + i) * K_ + kbase + j], acc[i][j]);
}

// ---------------------------------------------------------------------------
// Kernel D: val = agg - centers*softsum; intra-normalize over D; global L2.
// One block per b. Thread (k = tid&63, dg = tid>>6).
// ---------------------------------------------------------------------------
__global__ __launch_bounds__(256) void vlad_norm(const float* __restrict__ agg,
                                                 const float* __restrict__ centers,
                                                 const float* __restrict__ ss,
                                                 float* __restrict__ out) {
    const int b = blockIdx.x;
    const int k = threadIdx.x & 63;
    const int dg = threadIdx.x >> 6;
    const float s = ss[b * K_ + k];

    float sq = 0.f;
    for (int d = dg; d < D_; d += 4) {
        const float v = agg[((size_t)b * D_ + d) * K_ + k] - centers[d * K_ + k] * s;
        sq = fmaf(v, v, sq);
    }
    __shared__ float red[4][K_];
    __shared__ float inv1s[K_];
    __shared__ float col2[K_];
    __shared__ float inv2s;
    red[dg][k] = sq;
    __syncthreads();
    if (threadIdx.x < K_) {
        const float t = red[0][k] + red[1][k] + red[2][k] + red[3][k];
        const float n1 = sqrtf(t);
        const float den = fmaxf(n1, 1e-12f);
        const float i1 = 1.f / den;
        inv1s[k] = i1;
        const float c = n1 * i1;   // 1 if n1>eps, else n1/eps
        col2[k] = c * c;
    }
    __syncthreads();
    if (threadIdx.x == 0) {
        float t = 0.f;
        for (int kk = 0; kk < K_; ++kk) t += col2[kk];
        inv2s = 1.f / fmaxf(sqrtf(t), 1e-12f);
    }
    __syncthreads();
    const float i2 = inv2s;
    const float i1 = inv1s[k];
    for (int d = dg; d < D_; d += 4) {
        const float v = agg[((size_t)b * D_ + d) * K_ + k] - centers[d * K_ + k] * s;
        out[(size_t)b * (D_ * K_) + (size_t)d * K_ + k] = v * i1 * i2;
    }
}

// ---------------------------------------------------------------------------
extern "C" void kernel_launch(void* const* d_in, const int* in_sizes, int n_in,
                              void* d_out, int out_size, void* d_ws, size_t ws_size,
                              hipStream_t stream) {
    const float* X       = (const float*)d_in[0];  // [B, D, N]
    const float* W       = (const float*)d_in[1];  // [K, D]
    const float* bias    = (const float*)d_in[2];  // [K]
    const float* centers = (const float*)d_in[3];  // [D, K]
    float* out = (float*)d_out;

    char* ws = (char*)d_ws;
    const size_t pBytes   = (size_t)B_ * N_ * K_ * sizeof(float);   // 32 MB
    const size_t aggBytes = (size_t)B_ * D_ * K_ * sizeof(float);   // 4 MB
    float* P    = (float*)ws;
    float* agg  = (float*)(ws + pBytes);
    float* ssum = (float*)(ws + pBytes + aggBytes);

    hipMemsetAsync(agg, 0, aggBytes, stream);
    hipMemsetAsync(ssum, 0, (size_t)B_ * K_ * sizeof(float), stream);

    vlad_scores<<<dim3(N_ / 256, B_), 256, 0, stream>>>(X, W, bias, P);
    vlad_softsum<<<dim3(N_ / 256, B_), 256, 0, stream>>>(P, ssum);
    vlad_agg<<<dim3(8, D_ / DT, B_), 128, 0, stream>>>(X, P, agg);
    vlad_norm<<<B_, 256, 0, stream>>>(agg, centers, ssum, out);
}

// Round 3
// 534.760 us; speedup vs baseline: 1.5480x; 1.5480x over previous
//
#include <hip/hip_runtime.h>
#include <hip/hip_bf16.h>

#define B_ 32
#define D_ 512
#define K_ 64
#define N_ 4096

typedef __attribute__((ext_vector_type(8))) short short8;   // 8 bf16 (4 VGPRs)
typedef __attribute__((ext_vector_type(4))) short short4v;  // 4 bf16 (8 bytes)
typedef __attribute__((ext_vector_type(4))) float f32x4;

static __device__ __forceinline__ unsigned short f2bf(float f) {
    __hip_bfloat16 h = __float2bfloat16(f);
    return *reinterpret_cast<unsigned short*>(&h);
}

// ---------------------------------------------------------------------------
// Kernel A: scores = W @ X[b] + bias, softmax over K.
// One thread per n, 64 f32 accumulators (static-indexed -> registers).
// W staged transposed in LDS (uniform float4 reads = broadcast, free).
// Emits P bf16 in [b][k][n] layout (via LDS transpose) + per-block softsums.
// ---------------------------------------------------------------------------
__global__ __launch_bounds__(256) void vlad_scores(const float* __restrict__ X,
                                                   const float* __restrict__ W,
                                                   const float* __restrict__ bias,
                                                   unsigned short* __restrict__ P,
                                                   float* __restrict__ ssp) {
    __shared__ char smem[34048];  // max(Wl: 64*68*4 = 17408, T: 64*264*2 = 33792)
    float (*Wl)[68] = (float(*)[68])smem;  // [d][k], row = 272 B (17x16, aligned)

    const int b = blockIdx.y;
    const int nb = blockIdx.x;   // 0..15
    const int t = threadIdx.x;
    const int n = nb * 256 + t;

    float sc[64];
#pragma unroll
    for (int k = 0; k < 64; ++k) sc[k] = 0.f;

    const float* Xp = X + (size_t)b * D_ * N_ + n;

    for (int dsl = 0; dsl < 8; ++dsl) {
        __syncthreads();
        // stage W[k][dsl*64+d] -> Wl[d][k]  (transposed)
        {
            const int k = t & 63;
            const int dq = (t >> 6) * 4;
#pragma unroll
            for (int it = 0; it < 4; ++it) {
                const int d = dq + it * 16;
                const float4 wv = *(const float4*)&W[k * D_ + dsl * 64 + d];
                Wl[d + 0][k] = wv.x;
                Wl[d + 1][k] = wv.y;
                Wl[d + 2][k] = wv.z;
                Wl[d + 3][k] = wv.w;
            }
        }
        __syncthreads();
        for (int d = 0; d < 64; ++d) {
            const float x = Xp[(size_t)(dsl * 64 + d) * N_];
            const float4* wr = (const float4*)&Wl[d][0];
#pragma unroll
            for (int q = 0; q < 16; ++q) {
                const float4 w = wr[q];
                sc[q * 4 + 0] = fmaf(w.x, x, sc[q * 4 + 0]);
                sc[q * 4 + 1] = fmaf(w.y, x, sc[q * 4 + 1]);
                sc[q * 4 + 2] = fmaf(w.z, x, sc[q * 4 + 2]);
                sc[q * 4 + 3] = fmaf(w.w, x, sc[q * 4 + 3]);
            }
        }
    }

    // bias + softmax over k (all in registers)
    float m = -1e30f;
#pragma unroll
    for (int k = 0; k < 64; ++k) { sc[k] += bias[k]; m = fmaxf(m, sc[k]); }
    float esum = 0.f;
#pragma unroll
    for (int k = 0; k < 64; ++k) { sc[k] = __expf(sc[k] - m); esum += sc[k]; }
    const float inv = 1.f / esum;

    __syncthreads();
    // transpose via LDS: T[k][n-local] bf16, row = 528 B (33x16, aligned)
    unsigned short (*T)[264] = (unsigned short(*)[264])smem;
#pragma unroll
    for (int k = 0; k < 64; ++k) T[k][t] = f2bf(sc[k] * inv);
    __syncthreads();

    // coalesced bf16 row stores + per-block softsum (deterministic)
    const int k = t >> 2;
    const int c = t & 3;
    float s = 0.f;
    unsigned short* Pg = P + ((size_t)b * K_ + k) * N_ + nb * 256 + c * 64;
#pragma unroll
    for (int i = 0; i < 8; ++i) {
        const short8 v = *(const short8*)&T[k][c * 64 + i * 8];
#pragma unroll
        for (int j = 0; j < 8; ++j)
            s += __uint_as_float(((unsigned)(unsigned short)v[j]) << 16);
        *(short8*)&Pg[i * 8] = v;
    }
    s += __shfl_xor(s, 1);
    s += __shfl_xor(s, 2);
    if (c == 0) ssp[((size_t)b * 16 + nb) * K_ + k] = s;
}

// ---------------------------------------------------------------------------
// Kernel B: agg[d][k] = sum_n X[d][n] * P[k][n]  via MFMA 16x16x32 bf16.
// Contraction dim = n = contiguous dim of both operands -> transpose-free.
// Block: 256 thr (4 waves), tile 64d x 64k, stage 128 n/iter, XOR-swizzled LDS.
// n-split x2 into two agg buffers (no atomics).
// ---------------------------------------------------------------------------
__global__ __launch_bounds__(256) void vlad_agg(const float* __restrict__ X,
                                                const unsigned short* __restrict__ P,
                                                float* __restrict__ aggs) {
    __shared__ char XL[16384];  // [64 d][128 n] bf16, swizzled
    __shared__ char PL[16384];  // [64 k][128 n] bf16, swizzled

    const int ns = blockIdx.x;  // 0..1
    const int dt = blockIdx.y;  // 0..7
    const int b  = blockIdx.z;

    const int t = threadIdx.x;
    const int w = t >> 6;
    const int l = t & 63;
    const int lg = l >> 4;   // 0..3
    const int lr = l & 15;

    f32x4 acc[4];
#pragma unroll
    for (int kt = 0; kt < 4; ++kt) { acc[kt][0] = 0.f; acc[kt][1] = 0.f; acc[kt][2] = 0.f; acc[kt][3] = 0.f; }

    const float* Xb = X + ((size_t)b * D_ + dt * 64) * N_;
    const unsigned short* Pb = P + (size_t)b * K_ * N_;

    for (int st = 0; st < 16; ++st) {
        const int n0 = ns * 2048 + st * 128;
        __syncthreads();
        // stage X: [64 d][128 n] f32 -> bf16, row-XOR swizzle on 16B chunks
#pragma unroll
        for (int i = 0; i < 8; ++i) {
            const int idx = t + i * 256;
            const int row = idx >> 5;   // d-local (32 x 8B chunks per 256B row)
            const int c4 = idx & 31;    // float4 index in row
            const float4 v = *(const float4*)&Xb[(size_t)row * N_ + n0 + c4 * 4];
            short4v pk;
            pk[0] = (short)f2bf(v.x); pk[1] = (short)f2bf(v.y);
            pk[2] = (short)f2bf(v.z); pk[3] = (short)f2bf(v.w);
            *(short4v*)(XL + ((row * 256 + c4 * 8) ^ ((row & 7) << 4))) = pk;
        }
        // stage P: [64 k][128 n] bf16 (16 x 16B chunks per 256B row)
#pragma unroll
        for (int i = 0; i < 4; ++i) {
            const int idx = t + i * 256;
            const int kr = idx >> 4;    // FIX: was >>3 (LDS OOB + unstaged half-rows)
            const int c = idx & 15;     // FIX: was &7
            const short8 v = *(const short8*)&Pb[(size_t)kr * N_ + n0 + c * 8];
            *(short8*)(PL + ((kr * 256 + c * 16) ^ ((kr & 7) << 4))) = v;
        }
        __syncthreads();

        const int dl = w * 16 + lr;  // this lane's A row (d-local)
#pragma unroll
        for (int s = 0; s < 4; ++s) {
            const short8 a = *(const short8*)(XL + ((dl * 256 + s * 64 + lg * 16) ^ ((dl & 7) << 4)));
#pragma unroll
            for (int kt = 0; kt < 4; ++kt) {
                const int kl = kt * 16 + lr;
                const short8 bb = *(const short8*)(PL + ((kl * 256 + s * 64 + lg * 16) ^ ((kl & 7) << 4)));
                acc[kt] = __builtin_amdgcn_mfma_f32_16x16x32_bf16(a, bb, acc[kt], 0, 0, 0);
            }
        }
    }

    // C/D layout (m89-verified): row = lg*4 + r, col = lr
    float* ag = aggs + ((size_t)ns * B_ + b) * (D_ * K_) + (size_t)(dt * 64 + w * 16) * K_;
#pragma unroll
    for (int kt = 0; kt < 4; ++kt)
#pragma unroll
        for (int r = 0; r < 4; ++r)
            ag[(lg * 4 + r) * K_ + kt * 16 + lr] = acc[kt][r];
}

// ---------------------------------------------------------------------------
// Kernel D: val = (agg0+agg1) - centers*softsum; intra-D norm; global L2.
// ---------------------------------------------------------------------------
__global__ __launch_bounds__(256) void vlad_norm(const float* __restrict__ aggs,
                                                 const float* __restrict__ centers,
                                                 const float* __restrict__ ssp,
                                                 float* __restrict__ out) {
    const int b = blockIdx.x;
    const int t = threadIdx.x;
    const int k = t & 63;
    const int dg = t >> 6;

    __shared__ float ssL[64];
    __shared__ float red[4][64];
    __shared__ float inv1s[64];
    __shared__ float col2[64];
    __shared__ float inv2s;

    if (t < 64) {
        float s = 0.f;
        for (int i = 0; i < 16; ++i) s += ssp[((size_t)b * 16 + i) * K_ + k];
        ssL[k] = s;
    }
    __syncthreads();
    const float s = ssL[k];
    const float* a0 = aggs + (size_t)b * D_ * K_;
    const float* a1 = aggs + ((size_t)B_ + b) * D_ * K_;

    float sq = 0.f;
    for (int d = dg; d < D_; d += 4) {
        const float v = a0[d * K_ + k] + a1[d * K_ + k] - centers[d * K_ + k] * s;
        sq = fmaf(v, v, sq);
    }
    red[dg][k] = sq;
    __syncthreads();
    if (t < 64) {
        const float tt = red[0][k] + red[1][k] + red[2][k] + red[3][k];
        const float n1 = sqrtf(tt);
        const float i1 = 1.f / fmaxf(n1, 1e-12f);
        inv1s[k] = i1;
        const float c2 = n1 * i1;
        col2[k] = c2 * c2;
    }
    __syncthreads();
    if (t == 0) {
        float tt = 0.f;
        for (int kk = 0; kk < 64; ++kk) tt += col2[kk];
        inv2s = 1.f / fmaxf(sqrtf(tt), 1e-12f);
    }
    __syncthreads();
    const float i12 = inv1s[k] * inv2s;
    for (int d = dg; d < D_; d += 4)
        out[(size_t)b * (D_ * K_) + (size_t)d * K_ + k] =
            (a0[d * K_ + k] + a1[d * K_ + k] - centers[d * K_ + k] * s) * i12;
}

// ---------------------------------------------------------------------------
extern "C" void kernel_launch(void* const* d_in, const int* in_sizes, int n_in,
                              void* d_out, int out_size, void* d_ws, size_t ws_size,
                              hipStream_t stream) {
    const float* X       = (const float*)d_in[0];  // [B, D, N]
    const float* W       = (const float*)d_in[1];  // [K, D]
    const float* bias    = (const float*)d_in[2];  // [K]
    const float* centers = (const float*)d_in[3];  // [D, K]
    float* out = (float*)d_out;

    char* ws = (char*)d_ws;
    const size_t pBytes   = (size_t)B_ * K_ * N_ * sizeof(unsigned short);  // 16 MB
    const size_t aggBytes = (size_t)B_ * D_ * K_ * sizeof(float);           // 4 MB
    unsigned short* P = (unsigned short*)ws;
    float* aggs = (float*)(ws + pBytes);                 // 2 buffers (n-split)
    float* ssp  = (float*)(ws + pBytes + 2 * aggBytes);  // [B][16][K]

    vlad_scores<<<dim3(16, B_), 256, 0, stream>>>(X, W, bias, P, ssp);
    vlad_agg<<<dim3(2, 8, B_), 256, 0, stream>>>(X, P, aggs);
    vlad_norm<<<B_, 256, 0, stream>>>(aggs, centers, ssp, out);
}

// Round 4
// 368.217 us; speedup vs baseline: 2.2482x; 1.4523x over previous
//
#include <hip/hip_runtime.h>
#include <hip/hip_bf16.h>

#define B_ 32
#define D_ 512
#define K_ 64
#define N_ 4096

typedef __attribute__((ext_vector_type(8))) short short8;   // 8 bf16 (4 VGPRs)
typedef __attribute__((ext_vector_type(4))) short short4v;  // 4 bf16 (8 bytes)
typedef __attribute__((ext_vector_type(4))) float f32x4;

static __device__ __forceinline__ unsigned short f2bf(float f) {
    __hip_bfloat16 h = __float2bfloat16(f);
    return *reinterpret_cast<unsigned short*>(&h);
}

// ---------------------------------------------------------------------------
// Kernel A: scores = W @ X[b] + bias, softmax over K.
// One thread per n, 64 f32 accumulators (static-indexed -> registers).
// __launch_bounds__(256,4): VGPR cap 128 so the 64 accumulators actually live
// in registers (default heuristic capped at ~64 -> scratch spill, 7x stall).
// W staged transposed in LDS (float4 rows, wave-uniform -> broadcast).
// Emits P bf16 in [b][k][n] layout (via LDS transpose) + per-block softsums.
// ---------------------------------------------------------------------------
__global__ __launch_bounds__(256, 4) void vlad_scores(const float* __restrict__ X,
                                                      const float* __restrict__ W,
                                                      const float* __restrict__ bias,
                                                      unsigned short* __restrict__ P,
                                                      float* __restrict__ ssp) {
    __shared__ char smem[34048];  // max(Wl: 64*68*4 = 17408, T: 64*264*2 = 33792)
    float (*Wl)[68] = (float(*)[68])smem;  // [d][k], row = 272 B (17x16, aligned)

    const int b = blockIdx.y;
    const int nb = blockIdx.x;   // 0..15
    const int t = threadIdx.x;
    const int n = nb * 256 + t;

    float sc[64];
#pragma unroll
    for (int k = 0; k < 64; ++k) sc[k] = 0.f;

    const float* Xp = X + (size_t)b * D_ * N_ + n;

    for (int dsl = 0; dsl < 8; ++dsl) {
        __syncthreads();
        // stage W[k][dsl*64+d] -> Wl[d][k]  (transposed)
        {
            const int k = t & 63;
            const int dq = (t >> 6) * 4;
#pragma unroll
            for (int it = 0; it < 4; ++it) {
                const int d = dq + it * 16;
                const float4 wv = *(const float4*)&W[k * D_ + dsl * 64 + d];
                Wl[d + 0][k] = wv.x;
                Wl[d + 1][k] = wv.y;
                Wl[d + 2][k] = wv.z;
                Wl[d + 3][k] = wv.w;
            }
        }
        __syncthreads();
        for (int d = 0; d < 64; d += 2) {
            // both x loads hoisted: independent global loads overlap the FMAs
            const float x0 = Xp[(size_t)(dsl * 64 + d + 0) * N_];
            const float x1 = Xp[(size_t)(dsl * 64 + d + 1) * N_];
            const float4* wr0 = (const float4*)&Wl[d + 0][0];
            const float4* wr1 = (const float4*)&Wl[d + 1][0];
#pragma unroll
            for (int q = 0; q < 16; ++q) {
                const float4 w0 = wr0[q];
                sc[q * 4 + 0] = fmaf(w0.x, x0, sc[q * 4 + 0]);
                sc[q * 4 + 1] = fmaf(w0.y, x0, sc[q * 4 + 1]);
                sc[q * 4 + 2] = fmaf(w0.z, x0, sc[q * 4 + 2]);
                sc[q * 4 + 3] = fmaf(w0.w, x0, sc[q * 4 + 3]);
            }
#pragma unroll
            for (int q = 0; q < 16; ++q) {
                const float4 w1 = wr1[q];
                sc[q * 4 + 0] = fmaf(w1.x, x1, sc[q * 4 + 0]);
                sc[q * 4 + 1] = fmaf(w1.y, x1, sc[q * 4 + 1]);
                sc[q * 4 + 2] = fmaf(w1.z, x1, sc[q * 4 + 2]);
                sc[q * 4 + 3] = fmaf(w1.w, x1, sc[q * 4 + 3]);
            }
        }
    }

    // bias + softmax over k (all in registers)
    float m = -1e30f;
#pragma unroll
    for (int k = 0; k < 64; ++k) { sc[k] += bias[k]; m = fmaxf(m, sc[k]); }
    float esum = 0.f;
#pragma unroll
    for (int k = 0; k < 64; ++k) { sc[k] = __expf(sc[k] - m); esum += sc[k]; }
    const float inv = 1.f / esum;

    __syncthreads();
    // transpose via LDS: T[k][n-local] bf16, row = 528 B (33x16, aligned)
    unsigned short (*T)[264] = (unsigned short(*)[264])smem;
#pragma unroll
    for (int k = 0; k < 64; ++k) T[k][t] = f2bf(sc[k] * inv);
    __syncthreads();

    // coalesced bf16 row stores + per-block softsum (deterministic)
    const int k = t >> 2;
    const int c = t & 3;
    float s = 0.f;
    unsigned short* Pg = P + ((size_t)b * K_ + k) * N_ + nb * 256 + c * 64;
#pragma unroll
    for (int i = 0; i < 8; ++i) {
        const short8 v = *(const short8*)&T[k][c * 64 + i * 8];
#pragma unroll
        for (int j = 0; j < 8; ++j)
            s += __uint_as_float(((unsigned)(unsigned short)v[j]) << 16);
        *(short8*)&Pg[i * 8] = v;
    }
    s += __shfl_xor(s, 1);
    s += __shfl_xor(s, 2);
    if (c == 0) ssp[((size_t)b * 16 + nb) * K_ + k] = s;
}

// ---------------------------------------------------------------------------
// Kernel B: agg[d][k] = sum_n X[d][n] * P[k][n]  via MFMA 16x16x32 bf16.
// Contraction dim = n = contiguous dim of both operands -> transpose-free.
// Block: 256 thr (4 waves), tile 64d x 64k, stage 128 n/iter, XOR-swizzled LDS.
// n-split x2 into two agg buffers (no atomics).
// ---------------------------------------------------------------------------
__global__ __launch_bounds__(256) void vlad_agg(const float* __restrict__ X,
                                                const unsigned short* __restrict__ P,
                                                float* __restrict__ aggs) {
    __shared__ char XL[16384];  // [64 d][128 n] bf16, swizzled
    __shared__ char PL[16384];  // [64 k][128 n] bf16, swizzled

    const int ns = blockIdx.x;  // 0..1
    const int dt = blockIdx.y;  // 0..7
    const int b  = blockIdx.z;

    const int t = threadIdx.x;
    const int w = t >> 6;
    const int l = t & 63;
    const int lg = l >> 4;   // 0..3
    const int lr = l & 15;

    f32x4 acc[4];
#pragma unroll
    for (int kt = 0; kt < 4; ++kt) { acc[kt][0] = 0.f; acc[kt][1] = 0.f; acc[kt][2] = 0.f; acc[kt][3] = 0.f; }

    const float* Xb = X + ((size_t)b * D_ + dt * 64) * N_;
    const unsigned short* Pb = P + (size_t)b * K_ * N_;

    for (int st = 0; st < 16; ++st) {
        const int n0 = ns * 2048 + st * 128;
        __syncthreads();
        // stage X: [64 d][128 n] f32 -> bf16, row-XOR swizzle on 16B chunks
#pragma unroll
        for (int i = 0; i < 8; ++i) {
            const int idx = t + i * 256;
            const int row = idx >> 5;   // d-local (32 x 8B chunks per 256B row)
            const int c4 = idx & 31;    // float4 index in row
            const float4 v = *(const float4*)&Xb[(size_t)row * N_ + n0 + c4 * 4];
            short4v pk;
            pk[0] = (short)f2bf(v.x); pk[1] = (short)f2bf(v.y);
            pk[2] = (short)f2bf(v.z); pk[3] = (short)f2bf(v.w);
            *(short4v*)(XL + ((row * 256 + c4 * 8) ^ ((row & 7) << 4))) = pk;
        }
        // stage P: [64 k][128 n] bf16 (16 x 16B chunks per 256B row)
#pragma unroll
        for (int i = 0; i < 4; ++i) {
            const int idx = t + i * 256;
            const int kr = idx >> 4;
            const int c = idx & 15;
            const short8 v = *(const short8*)&Pb[(size_t)kr * N_ + n0 + c * 8];
            *(short8*)(PL + ((kr * 256 + c * 16) ^ ((kr & 7) << 4))) = v;
        }
        __syncthreads();

        const int dl = w * 16 + lr;  // this lane's A row (d-local)
#pragma unroll
        for (int s = 0; s < 4; ++s) {
            const short8 a = *(const short8*)(XL + ((dl * 256 + s * 64 + lg * 16) ^ ((dl & 7) << 4)));
#pragma unroll
            for (int kt = 0; kt < 4; ++kt) {
                const int kl = kt * 16 + lr;
                const short8 bb = *(const short8*)(PL + ((kl * 256 + s * 64 + lg * 16) ^ ((kl & 7) << 4)));
                acc[kt] = __builtin_amdgcn_mfma_f32_16x16x32_bf16(a, bb, acc[kt], 0, 0, 0);
            }
        }
    }

    // C/D layout (m89-verified): row = lg*4 + r, col = lr
    float* ag = aggs + ((size_t)ns * B_ + b) * (D_ * K_) + (size_t)(dt * 64 + w * 16) * K_;
#pragma unroll
    for (int kt = 0; kt < 4; ++kt)
#pragma unroll
        for (int r = 0; r < 4; ++r)
            ag[(lg * 4 + r) * K_ + kt * 16 + lr] = acc[kt][r];
}

// ---------------------------------------------------------------------------
// Kernel D: val = (agg0+agg1) - centers*softsum; intra-D norm; global L2.
// ---------------------------------------------------------------------------
__global__ __launch_bounds__(256) void vlad_norm(const float* __restrict__ aggs,
                                                 const float* __restrict__ centers,
                                                 const float* __restrict__ ssp,
                                                 float* __restrict__ out) {
    const int b = blockIdx.x;
    const int t = threadIdx.x;
    const int k = t & 63;
    const int dg = t >> 6;

    __shared__ float ssL[64];
    __shared__ float red[4][64];
    __shared__ float inv1s[64];
    __shared__ float col2[64];
    __shared__ float inv2s;

    if (t < 64) {
        float s = 0.f;
        for (int i = 0; i < 16; ++i) s += ssp[((size_t)b * 16 + i) * K_ + k];
        ssL[k] = s;
    }
    __syncthreads();
    const float s = ssL[k];
    const float* a0 = aggs + (size_t)b * D_ * K_;
    const float* a1 = aggs + ((size_t)B_ + b) * D_ * K_;

    float sq = 0.f;
    for (int d = dg; d < D_; d += 4) {
        const float v = a0[d * K_ + k] + a1[d * K_ + k] - centers[d * K_ + k] * s;
        sq = fmaf(v, v, sq);
    }
    red[dg][k] = sq;
    __syncthreads();
    if (t < 64) {
        const float tt = red[0][k] + red[1][k] + red[2][k] + red[3][k];
        const float n1 = sqrtf(tt);
        const float i1 = 1.f / fmaxf(n1, 1e-12f);
        inv1s[k] = i1;
        const float c2 = n1 * i1;
        col2[k] = c2 * c2;
    }
    __syncthreads();
    if (t == 0) {
        float tt = 0.f;
        for (int kk = 0; kk < 64; ++kk) tt += col2[kk];
        inv2s = 1.f / fmaxf(sqrtf(tt), 1e-12f);
    }
    __syncthreads();
    const float i12 = inv1s[k] * inv2s;
    for (int d = dg; d < D_; d += 4)
        out[(size_t)b * (D_ * K_) + (size_t)d * K_ + k] =
            (a0[d * K_ + k] + a1[d * K_ + k] - centers[d * K_ + k] * s) * i12;
}

// ---------------------------------------------------------------------------
extern "C" void kernel_launch(void* const* d_in, const int* in_sizes, int n_in,
                              void* d_out, int out_size, void* d_ws, size_t ws_size,
                              hipStream_t stream) {
    const float* X       = (const float*)d_in[0];  // [B, D, N]
    const float* W       = (const float*)d_in[1];  // [K, D]
    const float* bias    = (const float*)d_in[2];  // [K]
    const float* centers = (const float*)d_in[3];  // [D, K]
    float* out = (float*)d_out;

    char* ws = (char*)d_ws;
    const size_t pBytes   = (size_t)B_ * K_ * N_ * sizeof(unsigned short);  // 16 MB
    const size_t aggBytes = (size_t)B_ * D_ * K_ * sizeof(float);           // 4 MB
    unsigned short* P = (unsigned short*)ws;
    float* aggs = (float*)(ws + pBytes);                 // 2 buffers (n-split)
    float* ssp  = (float*)(ws + pBytes + 2 * aggBytes);  // [B][16][K]

    vlad_scores<<<dim3(16, B_), 256, 0, stream>>>(X, W, bias, P, ssp);
    vlad_agg<<<dim3(2, 8, B_), 256, 0, stream>>>(X, P, aggs);
    vlad_norm<<<B_, 256, 0, stream>>>(aggs, centers, ssp, out);
}

// Round 5
// 187.014 us; speedup vs baseline: 4.4265x; 1.9689x over previous
//
#include <hip/hip_runtime.h>
#include <hip/hip_bf16.h>

#define B_ 32
#define D_ 512
#define K_ 64
#define N_ 4096

typedef __attribute__((ext_vector_type(8))) short short8;   // 8 bf16 (4 VGPRs)
typedef __attribute__((ext_vector_type(4))) short short4v;  // 4 bf16 (8 bytes)
typedef __attribute__((ext_vector_type(4))) float f32x4;

static __device__ __forceinline__ unsigned short f2bf(float f) {
    __hip_bfloat16 h = __float2bfloat16(f);
    return *reinterpret_cast<unsigned short*>(&h);
}
static __device__ __forceinline__ float bf2f(unsigned short u) {
    return __uint_as_float(((unsigned)u) << 16);
}

// ---------------------------------------------------------------------------
// Kernel A (MFMA): scores = W @ X[b] + bias, softmax over K.
// Block = 4 waves, n-tile 64, all K=64. Contraction D=512 via 16x16x32 bf16.
// W -> LDS bf16 in two 256-d halves (32KB, XOR-swz); X-tile -> XT[n][d] bf16
// (8KB, XOR-swz) by reg-blocked 4x4 transpose. Softmax over k in-register
// (16 vals/lane + shfl_xor 16/32). P emitted [b][k][n] bf16 via LDS transpose
// + per-block softsum partials (no atomics). Only 16 acc f32/lane: no spill.
// ---------------------------------------------------------------------------
__global__ __launch_bounds__(256) void vlad_scores(const float* __restrict__ X,
                                                   const float* __restrict__ W,
                                                   const float* __restrict__ bias,
                                                   unsigned short* __restrict__ P,
                                                   float* __restrict__ ssp) {
    __shared__ unsigned short WL[64 * 256];  // 32KB: [64 k][256 d] bf16, 512B rows, XOR-swz
    __shared__ unsigned short XT[64 * 64];   // 8KB:  [64 n][64 d]  bf16, 128B rows, XOR-swz
    __shared__ unsigned short PLs[64 * 64];  // 8KB:  [64 k][64 n]  bf16, 128B rows, XOR-swz

    const int nb = blockIdx.x;   // 0..63
    const int b  = blockIdx.y;
    const int t  = threadIdx.x;
    const int w  = t >> 6;       // wave -> n-strip [w*16, w*16+16)
    const int l  = t & 63;
    const int lg = l >> 4;       // 0..3
    const int lr = l & 15;

    f32x4 acc[4];
#pragma unroll
    for (int kt = 0; kt < 4; ++kt) { acc[kt][0] = 0.f; acc[kt][1] = 0.f; acc[kt][2] = 0.f; acc[kt][3] = 0.f; }

    for (int dsl = 0; dsl < 8; ++dsl) {
        __syncthreads();
        // ---- stage W half (d in [half*256, half*256+256)) once per 4 stages
        if ((dsl & 3) == 0) {
            const int half = dsl >> 2;
#pragma unroll 4
            for (int j = 0; j < 16; ++j) {
                const int idx = t + j * 256;       // f4 index over [64 k][64 f4]
                const int k = idx >> 6;
                const int cf = idx & 63;           // f32 col = cf*4
                const float4 wv = *(const float4*)&W[k * D_ + half * 256 + cf * 4];
                const int C = cf >> 1;             // 16B chunk 0..31
                const int swz = (C & ~7) | ((C ^ k) & 7);
                short4v pk;
                pk[0] = (short)f2bf(wv.x); pk[1] = (short)f2bf(wv.y);
                pk[2] = (short)f2bf(wv.z); pk[3] = (short)f2bf(wv.w);
                *(short4v*)((char*)WL + k * 512 + (swz << 4) + (cf & 1) * 8) = pk;
            }
        }
        // ---- stage XT: transpose 64d x 64n tile (reg-blocked 4x4)
        {
            const int dq = t >> 4;   // 0..15 -> d0 = dq*4
            const int nq = t & 15;   // n0 = nq*4
            const float* Xs = X + (size_t)b * D_ * N_ + (size_t)(dsl * 64 + dq * 4) * N_ + nb * 64 + nq * 4;
            const float4 r0 = *(const float4*)&Xs[0 * N_];
            const float4 r1 = *(const float4*)&Xs[1 * N_];
            const float4 r2 = *(const float4*)&Xs[2 * N_];
            const float4 r3 = *(const float4*)&Xs[3 * N_];
            const float cs[4][4] = {{r0.x, r1.x, r2.x, r3.x},
                                    {r0.y, r1.y, r2.y, r3.y},
                                    {r0.z, r1.z, r2.z, r3.z},
                                    {r0.w, r1.w, r2.w, r3.w}};
#pragma unroll
            for (int c = 0; c < 4; ++c) {
                const int n = nq * 4 + c;
                short4v pk;
                pk[0] = (short)f2bf(cs[c][0]); pk[1] = (short)f2bf(cs[c][1]);
                pk[2] = (short)f2bf(cs[c][2]); pk[3] = (short)f2bf(cs[c][3]);
                const int C = dq >> 1;           // 16B chunk 0..7
                *(short4v*)((char*)XT + n * 128 + (((C ^ n) & 7) << 4) + (dq & 1) * 8) = pk;
            }
        }
        __syncthreads();
        // ---- 2 MFMA k-steps of 32 d each
#pragma unroll
        for (int kc = 0; kc < 2; ++kc) {
            const int n = w * 16 + lr;
            const int bC = kc * 4 + lg;          // XT chunk 0..7
            const short8 bfrag = *(const short8*)((char*)XT + n * 128 + (((bC ^ n) & 7) << 4));
#pragma unroll
            for (int kt = 0; kt < 4; ++kt) {
                const int k = kt * 16 + lr;
                const int aC = (dsl & 3) * 8 + kc * 4 + lg;   // WL chunk 0..31
                const int swz = (aC & ~7) | ((aC ^ k) & 7);
                const short8 afrag = *(const short8*)((char*)WL + k * 512 + (swz << 4));
                acc[kt] = __builtin_amdgcn_mfma_f32_16x16x32_bf16(afrag, bfrag, acc[kt], 0, 0, 0);
            }
        }
    }

    // ---- softmax over k: lane holds k = kt*16 + lg*4 + r for its n = w*16+lr
    float p[4][4];
    float m = -1e30f;
#pragma unroll
    for (int kt = 0; kt < 4; ++kt)
#pragma unroll
        for (int r = 0; r < 4; ++r) {
            p[kt][r] = acc[kt][r] + bias[kt * 16 + lg * 4 + r];
            m = fmaxf(m, p[kt][r]);
        }
    m = fmaxf(m, __shfl_xor(m, 16));
    m = fmaxf(m, __shfl_xor(m, 32));
    float sum = 0.f;
#pragma unroll
    for (int kt = 0; kt < 4; ++kt)
#pragma unroll
        for (int r = 0; r < 4; ++r) { p[kt][r] = __expf(p[kt][r] - m); sum += p[kt][r]; }
    sum += __shfl_xor(sum, 16);
    sum += __shfl_xor(sum, 32);
    const float inv = 1.f / sum;

    // ---- write P tile to LDS (bf16, XOR-swz rows)
    {
        const int n = w * 16 + lr;
#pragma unroll
        for (int kt = 0; kt < 4; ++kt)
#pragma unroll
            for (int r = 0; r < 4; ++r) {
                const int k = kt * 16 + lg * 4 + r;
                *(unsigned short*)((char*)PLs + k * 128 + ((((n >> 3) ^ k) & 7) << 4) + (n & 7) * 2) =
                    f2bf(p[kt][r] * inv);
            }
    }
    __syncthreads();

    // ---- coalesced P store + per-block softsum partial
    {
        const int k = t >> 2;
        const int c = t & 3;
        float s = 0.f;
        unsigned short* Pg = P + ((size_t)b * K_ + k) * N_ + nb * 64;
#pragma unroll
        for (int j = 0; j < 2; ++j) {
            const int C = c * 2 + j;
            const short8 v = *(const short8*)((char*)PLs + k * 128 + (((C ^ k) & 7) << 4));
#pragma unroll
            for (int e = 0; e < 8; ++e) s += bf2f((unsigned short)v[e]);
            *(short8*)&Pg[C * 8] = v;
        }
        s += __shfl_xor(s, 1);
        s += __shfl_xor(s, 2);
        if (c == 0) ssp[((size_t)b * 64 + nb) * K_ + k] = s;
    }
}

// ---------------------------------------------------------------------------
// Kernel B: agg[d][k] = sum_n X[d][n] * P[k][n]  via MFMA 16x16x32 bf16.
// (unchanged, validated)
// ---------------------------------------------------------------------------
__global__ __launch_bounds__(256) void vlad_agg(const float* __restrict__ X,
                                                const unsigned short* __restrict__ P,
                                                float* __restrict__ aggs) {
    __shared__ char XL[16384];  // [64 d][128 n] bf16, swizzled
    __shared__ char PL[16384];  // [64 k][128 n] bf16, swizzled

    const int ns = blockIdx.x;  // 0..1
    const int dt = blockIdx.y;  // 0..7
    const int b  = blockIdx.z;

    const int t = threadIdx.x;
    const int w = t >> 6;
    const int l = t & 63;
    const int lg = l >> 4;   // 0..3
    const int lr = l & 15;

    f32x4 acc[4];
#pragma unroll
    for (int kt = 0; kt < 4; ++kt) { acc[kt][0] = 0.f; acc[kt][1] = 0.f; acc[kt][2] = 0.f; acc[kt][3] = 0.f; }

    const float* Xb = X + ((size_t)b * D_ + dt * 64) * N_;
    const unsigned short* Pb = P + (size_t)b * K_ * N_;

    for (int st = 0; st < 16; ++st) {
        const int n0 = ns * 2048 + st * 128;
        __syncthreads();
#pragma unroll
        for (int i = 0; i < 8; ++i) {
            const int idx = t + i * 256;
            const int row = idx >> 5;
            const int c4 = idx & 31;
            const float4 v = *(const float4*)&Xb[(size_t)row * N_ + n0 + c4 * 4];
            short4v pk;
            pk[0] = (short)f2bf(v.x); pk[1] = (short)f2bf(v.y);
            pk[2] = (short)f2bf(v.z); pk[3] = (short)f2bf(v.w);
            *(short4v*)(XL + ((row * 256 + c4 * 8) ^ ((row & 7) << 4))) = pk;
        }
#pragma unroll
        for (int i = 0; i < 4; ++i) {
            const int idx = t + i * 256;
            const int kr = idx >> 4;
            const int c = idx & 15;
            const short8 v = *(const short8*)&Pb[(size_t)kr * N_ + n0 + c * 8];
            *(short8*)(PL + ((kr * 256 + c * 16) ^ ((kr & 7) << 4))) = v;
        }
        __syncthreads();

        const int dl = w * 16 + lr;
#pragma unroll
        for (int s = 0; s < 4; ++s) {
            const short8 a = *(const short8*)(XL + ((dl * 256 + s * 64 + lg * 16) ^ ((dl & 7) << 4)));
#pragma unroll
            for (int kt = 0; kt < 4; ++kt) {
                const int kl = kt * 16 + lr;
                const short8 bb = *(const short8*)(PL + ((kl * 256 + s * 64 + lg * 16) ^ ((kl & 7) << 4)));
                acc[kt] = __builtin_amdgcn_mfma_f32_16x16x32_bf16(a, bb, acc[kt], 0, 0, 0);
            }
        }
    }

    float* ag = aggs + ((size_t)ns * B_ + b) * (D_ * K_) + (size_t)(dt * 64 + w * 16) * K_;
#pragma unroll
    for (int kt = 0; kt < 4; ++kt)
#pragma unroll
        for (int r = 0; r < 4; ++r)
            ag[(lg * 4 + r) * K_ + kt * 16 + lr] = acc[kt][r];
}

// ---------------------------------------------------------------------------
// Kernel D: val = (agg0+agg1) - centers*softsum; intra-D norm; global L2.
// (ssp partials now 64 per b)
// ---------------------------------------------------------------------------
__global__ __launch_bounds__(256) void vlad_norm(const float* __restrict__ aggs,
                                                 const float* __restrict__ centers,
                                                 const float* __restrict__ ssp,
                                                 float* __restrict__ out) {
    const int b = blockIdx.x;
    const int t = threadIdx.x;
    const int k = t & 63;
    const int dg = t >> 6;

    __shared__ float ssL[64];
    __shared__ float red[4][64];
    __shared__ float inv1s[64];
    __shared__ float col2[64];
    __shared__ float inv2s;

    if (t < 64) {
        float s = 0.f;
        for (int i = 0; i < 64; ++i) s += ssp[((size_t)b * 64 + i) * K_ + k];
        ssL[k] = s;
    }
    __syncthreads();
    const float s = ssL[k];
    const float* a0 = aggs + (size_t)b * D_ * K_;
    const float* a1 = aggs + ((size_t)B_ + b) * D_ * K_;

    float sq = 0.f;
    for (int d = dg; d < D_; d += 4) {
        const float v = a0[d * K_ + k] + a1[d * K_ + k] - centers[d * K_ + k] * s;
        sq = fmaf(v, v, sq);
    }
    red[dg][k] = sq;
    __syncthreads();
    if (t < 64) {
        const float tt = red[0][k] + red[1][k] + red[2][k] + red[3][k];
        const float n1 = sqrtf(tt);
        const float i1 = 1.f / fmaxf(n1, 1e-12f);
        inv1s[k] = i1;
        const float c2 = n1 * i1;
        col2[k] = c2 * c2;
    }
    __syncthreads();
    if (t == 0) {
        float tt = 0.f;
        for (int kk = 0; kk < 64; ++kk) tt += col2[kk];
        inv2s = 1.f / fmaxf(sqrtf(tt), 1e-12f);
    }
    __syncthreads();
    const float i12 = inv1s[k] * inv2s;
    for (int d = dg; d < D_; d += 4)
        out[(size_t)b * (D_ * K_) + (size_t)d * K_ + k] =
            (a0[d * K_ + k] + a1[d * K_ + k] - centers[d * K_ + k] * s) * i12;
}

// ---------------------------------------------------------------------------
extern "C" void kernel_launch(void* const* d_in, const int* in_sizes, int n_in,
                              void* d_out, int out_size, void* d_ws, size_t ws_size,
                              hipStream_t stream) {
    const float* X       = (const float*)d_in[0];  // [B, D, N]
    const float* W       = (const float*)d_in[1];  // [K, D]
    const float* bias    = (const float*)d_in[2];  // [K]
    const float* centers = (const float*)d_in[3];  // [D, K]
    float* out = (float*)d_out;

    char* ws = (char*)d_ws;
    const size_t pBytes   = (size_t)B_ * K_ * N_ * sizeof(unsigned short);  // 16 MB
    const size_t aggBytes = (size_t)B_ * D_ * K_ * sizeof(float);           // 4 MB
    unsigned short* P = (unsigned short*)ws;
    float* aggs = (float*)(ws + pBytes);                 // 2 buffers (n-split)
    float* ssp  = (float*)(ws + pBytes + 2 * aggBytes);  // [B][64][K] = 512KB

    vlad_scores<<<dim3(64, B_), 256, 0, stream>>>(X, W, bias, P, ssp);
    vlad_agg<<<dim3(2, 8, B_), 256, 0, stream>>>(X, P, aggs);
    vlad_norm<<<B_, 256, 0, stream>>>(aggs, centers, ssp, out);
}

// Round 6
// 141.993 us; speedup vs baseline: 5.8300x; 1.3171x over previous
//
#include <hip/hip_runtime.h>
#include <hip/hip_bf16.h>

#define B_ 32
#define D_ 512
#define K_ 64
#define N_ 4096

typedef __attribute__((ext_vector_type(8))) short short8;   // 8 bf16 (4 VGPRs)
typedef __attribute__((ext_vector_type(4))) short short4v;  // 4 bf16 (8 bytes)
typedef __attribute__((ext_vector_type(4))) float f32x4;

static __device__ __forceinline__ unsigned short f2bf(float f) {
    __hip_bfloat16 h = __float2bfloat16(f);
    return *reinterpret_cast<unsigned short*>(&h);
}
static __device__ __forceinline__ float bf2f(unsigned short u) {
    return __uint_as_float(((unsigned)u) << 16);
}

// ---------------------------------------------------------------------------
// Kernel A (MFMA, pipelined): scores = W @ X[b] + bias, softmax over K.
// Full W in LDS bf16 (64KB, staged once). XT double-buffered (2x8KB): loads
// for stage dsl+1 issue before stage dsl's MFMAs; ONE sync per stage
// (stage dsl reads buf dsl&1, writes buf (dsl+1)&1; the stage-end sync
// separates the only cross-use). PLs aliases the XT region after the loop.
// LDS 80KB -> 2 blocks/CU. Softmax in-register (validated R5 mapping).
// ---------------------------------------------------------------------------
__global__ __launch_bounds__(256, 2) void vlad_scores(const float* __restrict__ X,
                                                      const float* __restrict__ W,
                                                      const float* __restrict__ bias,
                                                      unsigned short* __restrict__ P,
                                                      float* __restrict__ ssp) {
    __shared__ unsigned short WL[64 * 512];    // 64KB: [64 k][512 d] bf16, 1KB rows, XOR-swz
    __shared__ unsigned short XTb[2][64 * 64]; // 16KB: 2 x [64 n][64 d] bf16, 128B rows, XOR-swz

    const int nb = blockIdx.x;   // 0..63
    const int b  = blockIdx.y;
    const int t  = threadIdx.x;
    const int w  = t >> 6;       // wave -> n-strip [w*16, w*16+16)
    const int l  = t & 63;
    const int lg = l >> 4;       // 0..3
    const int lr = l & 15;

    // ---- stage full W -> WL (once per block; L2-hot after first blocks)
#pragma unroll 8
    for (int j = 0; j < 32; ++j) {
        const int idx = t + j * 256;       // f4 index over [64 k][128 f4]
        const int k = idx >> 7;
        const int cf = idx & 127;          // f32 col = cf*4
        const float4 wv = *(const float4*)&W[k * D_ + cf * 4];
        const int C = cf >> 1;             // 16B chunk 0..63
        const int swz = (C & ~7) | ((C ^ k) & 7);
        short4v pk;
        pk[0] = (short)f2bf(wv.x); pk[1] = (short)f2bf(wv.y);
        pk[2] = (short)f2bf(wv.z); pk[3] = (short)f2bf(wv.w);
        *(short4v*)((char*)WL + k * 1024 + (swz << 4) + (cf & 1) * 8) = pk;
    }

    const int dq = t >> 4;   // 0..15 -> d0 = dq*4
    const int nq = t & 15;   // n0 = nq*4
    const float* Xs0 = X + (size_t)b * D_ * N_ + nb * 64 + nq * 4;

    // transpose-write 4x4 reg block into XT buffer `buf`
    auto xt_write = [&](int buf, const float4& a0, const float4& a1,
                        const float4& a2, const float4& a3) {
        const float cs[4][4] = {{a0.x, a1.x, a2.x, a3.x},
                                {a0.y, a1.y, a2.y, a3.y},
                                {a0.z, a1.z, a2.z, a3.z},
                                {a0.w, a1.w, a2.w, a3.w}};
#pragma unroll
        for (int c = 0; c < 4; ++c) {
            const int n = nq * 4 + c;
            short4v pk;
            pk[0] = (short)f2bf(cs[c][0]); pk[1] = (short)f2bf(cs[c][1]);
            pk[2] = (short)f2bf(cs[c][2]); pk[3] = (short)f2bf(cs[c][3]);
            const int C = dq >> 1;         // 16B chunk 0..7
            *(short4v*)((char*)XTb + buf * 8192 + n * 128 +
                        (((C ^ n) & 7) << 4) + (dq & 1) * 8) = pk;
        }
    };

    // ---- prologue: load + write stage 0
    {
        const float* Xs = Xs0 + (size_t)(dq * 4) * N_;
        const float4 a0 = *(const float4*)&Xs[0 * N_];
        const float4 a1 = *(const float4*)&Xs[1 * N_];
        const float4 a2 = *(const float4*)&Xs[2 * N_];
        const float4 a3 = *(const float4*)&Xs[3 * N_];
        xt_write(0, a0, a1, a2, a3);
    }
    __syncthreads();

    f32x4 acc[4];
#pragma unroll
    for (int kt = 0; kt < 4; ++kt) { acc[kt][0] = 0.f; acc[kt][1] = 0.f; acc[kt][2] = 0.f; acc[kt][3] = 0.f; }

    for (int dsl = 0; dsl < 8; ++dsl) {
        // issue next stage's loads first (overlap with MFMA below)
        float4 s0, s1, s2, s3;
        if (dsl < 7) {
            const float* Xs = Xs0 + (size_t)((dsl + 1) * 64 + dq * 4) * N_;
            s0 = *(const float4*)&Xs[0 * N_];
            s1 = *(const float4*)&Xs[1 * N_];
            s2 = *(const float4*)&Xs[2 * N_];
            s3 = *(const float4*)&Xs[3 * N_];
        }
        // MFMA on XTb[dsl&1], WL d-range [dsl*64, dsl*64+64)
        const int cur = dsl & 1;
        const int n = w * 16 + lr;
#pragma unroll
        for (int kc = 0; kc < 2; ++kc) {
            const int bC = kc * 4 + lg;    // XT chunk 0..7
            const short8 bfrag = *(const short8*)((char*)XTb + cur * 8192 + n * 128 +
                                                  (((bC ^ n) & 7) << 4));
#pragma unroll
            for (int kt = 0; kt < 4; ++kt) {
                const int k = kt * 16 + lr;
                const int aC = dsl * 8 + kc * 4 + lg;   // WL chunk 0..63
                const int swz = (aC & ~7) | ((aC ^ k) & 7);
                const short8 afrag = *(const short8*)((char*)WL + k * 1024 + (swz << 4));
                acc[kt] = __builtin_amdgcn_mfma_f32_16x16x32_bf16(afrag, bfrag, acc[kt], 0, 0, 0);
            }
        }
        if (dsl < 7) {
            xt_write((dsl + 1) & 1, s0, s1, s2, s3);
            __syncthreads();
        }
    }

    // ---- softmax over k: lane holds k = kt*16 + lg*4 + r for its n = w*16+lr
    float p[4][4];
    float m = -1e30f;
#pragma unroll
    for (int kt = 0; kt < 4; ++kt)
#pragma unroll
        for (int r = 0; r < 4; ++r) {
            p[kt][r] = acc[kt][r] + bias[kt * 16 + lg * 4 + r];
            m = fmaxf(m, p[kt][r]);
        }
    m = fmaxf(m, __shfl_xor(m, 16));
    m = fmaxf(m, __shfl_xor(m, 32));
    float sum = 0.f;
#pragma unroll
    for (int kt = 0; kt < 4; ++kt)
#pragma unroll
        for (int r = 0; r < 4; ++r) { p[kt][r] = __expf(p[kt][r] - m); sum += p[kt][r]; }
    sum += __shfl_xor(sum, 16);
    sum += __shfl_xor(sum, 32);
    const float inv = 1.f / sum;

    // ---- write P tile to LDS (aliases XT region; sync guards last MFMA reads)
    __syncthreads();
    unsigned short* PLs = &XTb[0][0];   // 8KB used: [64 k][64 n] bf16, 128B rows, XOR-swz
    {
        const int n = w * 16 + lr;
#pragma unroll
        for (int kt = 0; kt < 4; ++kt)
#pragma unroll
            for (int r = 0; r < 4; ++r) {
                const int k = kt * 16 + lg * 4 + r;
                *(unsigned short*)((char*)PLs + k * 128 + ((((n >> 3) ^ k) & 7) << 4) + (n & 7) * 2) =
                    f2bf(p[kt][r] * inv);
            }
    }
    __syncthreads();

    // ---- coalesced P store + per-block softsum partial
    {
        const int k = t >> 2;
        const int c = t & 3;
        float s = 0.f;
        unsigned short* Pg = P + ((size_t)b * K_ + k) * N_ + nb * 64;
#pragma unroll
        for (int j = 0; j < 2; ++j) {
            const int C = c * 2 + j;
            const short8 v = *(const short8*)((char*)PLs + k * 128 + (((C ^ k) & 7) << 4));
#pragma unroll
            for (int e = 0; e < 8; ++e) s += bf2f((unsigned short)v[e]);
            *(short8*)&Pg[C * 8] = v;
        }
        s += __shfl_xor(s, 1);
        s += __shfl_xor(s, 2);
        if (c == 0) ssp[((size_t)b * 64 + nb) * K_ + k] = s;
    }
}

// ---------------------------------------------------------------------------
// Kernel B: agg[d][k] = sum_n X[d][n] * P[k][n]  via MFMA 16x16x32 bf16.
// (unchanged, validated)
// ---------------------------------------------------------------------------
__global__ __launch_bounds__(256) void vlad_agg(const float* __restrict__ X,
                                                const unsigned short* __restrict__ P,
                                                float* __restrict__ aggs) {
    __shared__ char XL[16384];  // [64 d][128 n] bf16, swizzled
    __shared__ char PL[16384];  // [64 k][128 n] bf16, swizzled

    const int ns = blockIdx.x;  // 0..1
    const int dt = blockIdx.y;  // 0..7
    const int b  = blockIdx.z;

    const int t = threadIdx.x;
    const int w = t >> 6;
    const int l = t & 63;
    const int lg = l >> 4;   // 0..3
    const int lr = l & 15;

    f32x4 acc[4];
#pragma unroll
    for (int kt = 0; kt < 4; ++kt) { acc[kt][0] = 0.f; acc[kt][1] = 0.f; acc[kt][2] = 0.f; acc[kt][3] = 0.f; }

    const float* Xb = X + ((size_t)b * D_ + dt * 64) * N_;
    const unsigned short* Pb = P + (size_t)b * K_ * N_;

    for (int st = 0; st < 16; ++st) {
        const int n0 = ns * 2048 + st * 128;
        __syncthreads();
#pragma unroll
        for (int i = 0; i < 8; ++i) {
            const int idx = t + i * 256;
            const int row = idx >> 5;
            const int c4 = idx & 31;
            const float4 v = *(const float4*)&Xb[(size_t)row * N_ + n0 + c4 * 4];
            short4v pk;
            pk[0] = (short)f2bf(v.x); pk[1] = (short)f2bf(v.y);
            pk[2] = (short)f2bf(v.z); pk[3] = (short)f2bf(v.w);
            *(short4v*)(XL + ((row * 256 + c4 * 8) ^ ((row & 7) << 4))) = pk;
        }
#pragma unroll
        for (int i = 0; i < 4; ++i) {
            const int idx = t + i * 256;
            const int kr = idx >> 4;
            const int c = idx & 15;
            const short8 v = *(const short8*)&Pb[(size_t)kr * N_ + n0 + c * 8];
            *(short8*)(PL + ((kr * 256 + c * 16) ^ ((kr & 7) << 4))) = v;
        }
        __syncthreads();

        const int dl = w * 16 + lr;
#pragma unroll
        for (int s = 0; s < 4; ++s) {
            const short8 a = *(const short8*)(XL + ((dl * 256 + s * 64 + lg * 16) ^ ((dl & 7) << 4)));
#pragma unroll
            for (int kt = 0; kt < 4; ++kt) {
                const int kl = kt * 16 + lr;
                const short8 bb = *(const short8*)(PL + ((kl * 256 + s * 64 + lg * 16) ^ ((kl & 7) << 4)));
                acc[kt] = __builtin_amdgcn_mfma_f32_16x16x32_bf16(a, bb, acc[kt], 0, 0, 0);
            }
        }
    }

    float* ag = aggs + ((size_t)ns * B_ + b) * (D_ * K_) + (size_t)(dt * 64 + w * 16) * K_;
#pragma unroll
    for (int kt = 0; kt < 4; ++kt)
#pragma unroll
        for (int r = 0; r < 4; ++r)
            ag[(lg * 4 + r) * K_ + kt * 16 + lr] = acc[kt][r];
}

// ---------------------------------------------------------------------------
// Kernel D1: deterministic per-d-slice partial sum of squares -> nrmp[b][8][k]
// grid (8, 32): 8x more parallelism than the old single-block-per-b norm.
// ---------------------------------------------------------------------------
__global__ __launch_bounds__(256) void vlad_norm1(const float* __restrict__ aggs,
                                                  const float* __restrict__ centers,
                                                  const float* __restrict__ ssp,
                                                  float* __restrict__ nrmp) {
    const int ds = blockIdx.x;  // 0..7
    const int b  = blockIdx.y;
    const int t  = threadIdx.x;
    const int k  = t & 63;
    const int dg = t >> 6;

    __shared__ float red[4][64];

    // ssp reduce (all 256 threads)
    float s0 = 0.f;
#pragma unroll
    for (int j = 0; j < 16; ++j) s0 += ssp[((size_t)b * 64 + (dg + j * 4)) * K_ + k];
    red[dg][k] = s0;
    __syncthreads();
    const float s = red[0][k] + red[1][k] + red[2][k] + red[3][k];
    __syncthreads();

    const float* a0 = aggs + (size_t)b * D_ * K_;
    const float* a1 = aggs + ((size_t)B_ + b) * D_ * K_;
    float sq = 0.f;
    for (int d = ds * 64 + dg; d < ds * 64 + 64; d += 4) {
        const float v = a0[d * K_ + k] + a1[d * K_ + k] - centers[d * K_ + k] * s;
        sq = fmaf(v, v, sq);
    }
    red[dg][k] = sq;
    __syncthreads();
    if (t < 64) nrmp[((size_t)b * 8 + ds) * K_ + k] =
        red[0][k] + red[1][k] + red[2][k] + red[3][k];
}

// ---------------------------------------------------------------------------
// Kernel D2: finalize norms (intra-D + global L2), scale, write out.
// ---------------------------------------------------------------------------
__global__ __launch_bounds__(256) void vlad_norm2(const float* __restrict__ aggs,
                                                  const float* __restrict__ centers,
                                                  const float* __restrict__ ssp,
                                                  const float* __restrict__ nrmp,
                                                  float* __restrict__ out) {
    const int ds = blockIdx.x;  // 0..7
    const int b  = blockIdx.y;
    const int t  = threadIdx.x;
    const int k  = t & 63;
    const int dg = t >> 6;

    __shared__ float red[4][64];
    __shared__ float inv1s[64];
    __shared__ float col2[64];
    __shared__ float inv2s;

    float s0 = 0.f;
#pragma unroll
    for (int j = 0; j < 16; ++j) s0 += ssp[((size_t)b * 64 + (dg + j * 4)) * K_ + k];
    red[dg][k] = s0;
    __syncthreads();
    const float s = red[0][k] + red[1][k] + red[2][k] + red[3][k];

    if (t < 64) {
        float tt = 0.f;
#pragma unroll
        for (int i = 0; i < 8; ++i) tt += nrmp[((size_t)b * 8 + i) * K_ + k];
        const float n1 = sqrtf(tt);
        const float i1 = 1.f / fmaxf(n1, 1e-12f);
        inv1s[k] = i1;
        const float c2 = n1 * i1;
        col2[k] = c2 * c2;
    }
    __syncthreads();
    if (t == 0) {
        float tt = 0.f;
        for (int kk = 0; kk < 64; ++kk) tt += col2[kk];
        inv2s = 1.f / fmaxf(sqrtf(tt), 1e-12f);
    }
    __syncthreads();
    const float i12 = inv1s[k] * inv2s;

    const float* a0 = aggs + (size_t)b * D_ * K_;
    const float* a1 = aggs + ((size_t)B_ + b) * D_ * K_;
    for (int d = ds * 64 + dg; d < ds * 64 + 64; d += 4)
        out[(size_t)b * (D_ * K_) + (size_t)d * K_ + k] =
            (a0[d * K_ + k] + a1[d * K_ + k] - centers[d * K_ + k] * s) * i12;
}

// ---------------------------------------------------------------------------
extern "C" void kernel_launch(void* const* d_in, const int* in_sizes, int n_in,
                              void* d_out, int out_size, void* d_ws, size_t ws_size,
                              hipStream_t stream) {
    const float* X       = (const float*)d_in[0];  // [B, D, N]
    const float* W       = (const float*)d_in[1];  // [K, D]
    const float* bias    = (const float*)d_in[2];  // [K]
    const float* centers = (const float*)d_in[3];  // [D, K]
    float* out = (float*)d_out;

    char* ws = (char*)d_ws;
    const size_t pBytes   = (size_t)B_ * K_ * N_ * sizeof(unsigned short);  // 16 MB
    const size_t aggBytes = (size_t)B_ * D_ * K_ * sizeof(float);           // 4 MB
    unsigned short* P = (unsigned short*)ws;
    float* aggs = (float*)(ws + pBytes);                           // 2 buffers (n-split)
    float* ssp  = (float*)(ws + pBytes + 2 * aggBytes);            // [B][64][K] = 512KB
    float* nrmp = (float*)(ws + pBytes + 2 * aggBytes + (size_t)B_ * 64 * K_ * 4);  // [B][8][K]

    vlad_scores<<<dim3(64, B_), 256, 0, stream>>>(X, W, bias, P, ssp);
    vlad_agg<<<dim3(2, 8, B_), 256, 0, stream>>>(X, P, aggs);
    vlad_norm1<<<dim3(8, B_), 256, 0, stream>>>(aggs, centers, ssp, nrmp);
    vlad_norm2<<<dim3(8, B_), 256, 0, stream>>>(aggs, centers, ssp, nrmp, out);
}

// Round 7
// 108.737 us; speedup vs baseline: 7.6130x; 1.3058x over previous
//
#include <hip/hip_runtime.h>
#include <hip/hip_bf16.h>

#define B_ 32
#define D_ 512
#define K_ 64
#define N_ 4096

typedef __attribute__((ext_vector_type(8))) short short8;   // 8 bf16 (4 VGPRs)
typedef __attribute__((ext_vector_type(4))) short short4v;  // 4 bf16 (8 bytes)
typedef __attribute__((ext_vector_type(4))) float f32x4;

static __device__ __forceinline__ unsigned short f2bf(float f) {
    __hip_bfloat16 h = __float2bfloat16(f);
    return *reinterpret_cast<unsigned short*>(&h);
}
static __device__ __forceinline__ float bf2f(unsigned short u) {
    return __uint_as_float(((unsigned)u) << 16);
}

// LDS carve (bytes): WL 64K | XL 64K | XT 2x8K | PT 8K | smx 512 | ssm 512
#define SMEM_BYTES 156672
#define WL_OFF 0
#define XL_OFF 65536
#define XT_OFF 131072
#define PT_OFF 147456
#define SMX_OFF 155648
#define SSM_OFF 156160

// ---------------------------------------------------------------------------
// Fused kernel: per n-tile of 64 -> scores MFMA (contraction D, via XT) ->
// in-register softmax (cross-wave-half exchange) -> P tile in LDS ->
// agg MFMA (contraction n, via XL) accumulating in VGPRs across 8 n-tiles.
// X is read from HBM exactly once; P never goes to global.
// Block: 512 thr (8 waves), 1 block/CU (153KB LDS). Grid: 8 ns x 32 b.
// Wave roles: strip = w&3 (n-strip of 16), khalf = w>>2 (k-half for scores);
// agg: wave w owns d-rows [w*64, w*64+64).
// All MFMA layout/swizzle formulas verbatim from validated R5/R6 kernels.
// ---------------------------------------------------------------------------
__global__ __launch_bounds__(512, 2) void vlad_fused(const float* __restrict__ X,
                                                     const float* __restrict__ W,
                                                     const float* __restrict__ bias,
                                                     float* __restrict__ aggs,
                                                     float* __restrict__ ssp) {
    extern __shared__ char smem[];
    char* WLp = smem + WL_OFF;
    char* XLp = smem + XL_OFF;
    char* XTp = smem + XT_OFF;
    char* PTp = smem + PT_OFF;
    float* smx = (float*)(smem + SMX_OFF);   // [8 waves][16 lr]
    float* ssm = (float*)(smem + SSM_OFF);

    const int ns = blockIdx.x;   // 0..7  (n-range [ns*512, ns*512+512))
    const int b  = blockIdx.y;
    const int t  = threadIdx.x;
    const int w  = t >> 6;
    const int l  = t & 63;
    const int lg = l >> 4;
    const int lr = l & 15;
    const int strip = w & 3;
    const int khalf = w >> 2;

    // ---- stage full W -> WL [64 k][512 d] bf16, 1KB rows, XOR-swz (R6 formula)
#pragma unroll 4
    for (int j = 0; j < 16; ++j) {
        const int idx = t + j * 512;       // f4 index over [64 k][128 f4]
        const int k = idx >> 7;
        const int cf = idx & 127;
        const float4 wv = *(const float4*)&W[k * D_ + cf * 4];
        const int C = cf >> 1;
        const int swz = (C & ~7) | ((C ^ k) & 7);
        short4v pk;
        pk[0] = (short)f2bf(wv.x); pk[1] = (short)f2bf(wv.y);
        pk[2] = (short)f2bf(wv.z); pk[3] = (short)f2bf(wv.w);
        *(short4v*)(WLp + k * 1024 + (swz << 4) + (cf & 1) * 8) = pk;
    }

    // bias for this lane's 8 score slots
    float bias_r[2][4];
#pragma unroll
    for (int ktl = 0; ktl < 2; ++ktl)
#pragma unroll
        for (int r = 0; r < 4; ++r)
            bias_r[ktl][r] = bias[khalf * 32 + ktl * 16 + lg * 4 + r];

    // agg accumulators: wave's 64 d-rows x 64 k
    f32x4 aacc[4][4];
#pragma unroll
    for (int m = 0; m < 4; ++m)
#pragma unroll
        for (int kt = 0; kt < 4; ++kt) {
            aacc[m][kt][0] = 0.f; aacc[m][kt][1] = 0.f;
            aacc[m][kt][2] = 0.f; aacc[m][kt][3] = 0.f;
        }
    float ss_acc = 0.f;   // per-thread chunk-partial of softsum (k = t>>3)

    // staging role: 2 d-rows x 4 n-cols per thread
    const int dq2 = t >> 4;   // 0..31 -> local d0 = dq2*2
    const int nq  = t & 15;   // n0 = nq*4
    const float* Xbase = X + (size_t)b * D_ * N_ + ns * 512 + nq * 4;

    // write one staged 2x4 block into XL (global-d row) + XT[buf] (transposed)
    auto stage_write = [&](int buf, int dglob0, const float4& r0, const float4& r1) {
        const float e0[4] = {r0.x, r0.y, r0.z, r0.w};
        const float e1[4] = {r1.x, r1.y, r1.z, r1.w};
        // XL rows dglob0, dglob0+1 (128B rows, chunk C = nq>>1)
        {
            short4v pk;
            pk[0] = (short)f2bf(e0[0]); pk[1] = (short)f2bf(e0[1]);
            pk[2] = (short)f2bf(e0[2]); pk[3] = (short)f2bf(e0[3]);
            const int d = dglob0;
            *(short4v*)(XLp + d * 128 + ((((nq >> 1) ^ d) & 7) << 4) + (nq & 1) * 8) = pk;
        }
        {
            short4v pk;
            pk[0] = (short)f2bf(e1[0]); pk[1] = (short)f2bf(e1[1]);
            pk[2] = (short)f2bf(e1[2]); pk[3] = (short)f2bf(e1[3]);
            const int d = dglob0 + 1;
            *(short4v*)(XLp + d * 128 + ((((nq >> 1) ^ d) & 7) << 4) + (nq & 1) * 8) = pk;
        }
        // XT[buf] rows n0..n0+3, byte col dq2*4 (chunk C = dq2>>2)
#pragma unroll
        for (int c = 0; c < 4; ++c) {
            const int n = nq * 4 + c;
            const unsigned v = (unsigned)f2bf(e0[c]) | ((unsigned)f2bf(e1[c]) << 16);
            *(unsigned*)(XTp + buf * 8192 + n * 128 +
                         ((((dq2 >> 2) ^ n) & 7) << 4) + (dq2 & 3) * 4) = v;
        }
    };

    __syncthreads();   // WL ready

    for (int nt = 0; nt < 8; ++nt) {
        const int nbase = nt * 64;

        // ---- stage d-chunk 0
        {
            const float* Xs = Xbase + nbase + (size_t)(dq2 * 2) * N_;
            const float4 r0 = *(const float4*)&Xs[0];
            const float4 r1 = *(const float4*)&Xs[N_];
            stage_write(0, dq2 * 2, r0, r1);
        }
        __syncthreads();

        f32x4 sacc[2];
#pragma unroll
        for (int ktl = 0; ktl < 2; ++ktl) {
            sacc[ktl][0] = 0.f; sacc[ktl][1] = 0.f; sacc[ktl][2] = 0.f; sacc[ktl][3] = 0.f;
        }

        // ---- scores over D=512 in 8 chunks, XT double-buffered
        for (int dsl = 0; dsl < 8; ++dsl) {
            const int cur = dsl & 1;
            float4 p0, p1;
            if (dsl < 7) {
                const float* Xs = Xbase + nbase + (size_t)((dsl + 1) * 64 + dq2 * 2) * N_;
                p0 = *(const float4*)&Xs[0];
                p1 = *(const float4*)&Xs[N_];
            }
            const int n = strip * 16 + lr;
#pragma unroll
            for (int kc = 0; kc < 2; ++kc) {
                const int bC = kc * 4 + lg;
                const short8 bfrag = *(const short8*)(XTp + cur * 8192 + n * 128 +
                                                      (((bC ^ n) & 7) << 4));
#pragma unroll
                for (int ktl = 0; ktl < 2; ++ktl) {
                    const int k = khalf * 32 + ktl * 16 + lr;
                    const int aC = dsl * 8 + kc * 4 + lg;
                    const int swz = (aC & ~7) | ((aC ^ k) & 7);
                    const short8 afrag = *(const short8*)(WLp + k * 1024 + (swz << 4));
                    sacc[ktl] = __builtin_amdgcn_mfma_f32_16x16x32_bf16(afrag, bfrag, sacc[ktl], 0, 0, 0);
                }
            }
            if (dsl < 7) {
                stage_write(cur ^ 1, (dsl + 1) * 64 + dq2 * 2, p0, p1);
                __syncthreads();
            }
        }

        // ---- softmax over k (lane: k = khalf*32 + ktl*16 + lg*4 + r, n = strip*16+lr)
        float p[2][4];
        float mx = -1e30f;
#pragma unroll
        for (int ktl = 0; ktl < 2; ++ktl)
#pragma unroll
            for (int r = 0; r < 4; ++r) {
                p[ktl][r] = sacc[ktl][r] + bias_r[ktl][r];
                mx = fmaxf(mx, p[ktl][r]);
            }
        mx = fmaxf(mx, __shfl_xor(mx, 16));
        mx = fmaxf(mx, __shfl_xor(mx, 32));
        if (l < 16) smx[w * 16 + lr] = mx;
        __syncthreads();
        mx = fmaxf(mx, smx[(w ^ 4) * 16 + lr]);
        float sum = 0.f;
#pragma unroll
        for (int ktl = 0; ktl < 2; ++ktl)
#pragma unroll
            for (int r = 0; r < 4; ++r) { p[ktl][r] = __expf(p[ktl][r] - mx); sum += p[ktl][r]; }
        sum += __shfl_xor(sum, 16);
        sum += __shfl_xor(sum, 32);
        if (l < 16) ssm[w * 16 + lr] = sum;
        __syncthreads();
        sum += ssm[(w ^ 4) * 16 + lr];
        const float inv = 1.f / sum;

        // ---- P tile -> LDS [64 k][64 n] bf16 (R5-validated swizzle)
        {
            const int n = strip * 16 + lr;
#pragma unroll
            for (int ktl = 0; ktl < 2; ++ktl)
#pragma unroll
                for (int r = 0; r < 4; ++r) {
                    const int k = khalf * 32 + ktl * 16 + lg * 4 + r;
                    *(unsigned short*)(PTp + k * 128 + ((((n >> 3) ^ k) & 7) << 4) + (n & 7) * 2) =
                        f2bf(p[ktl][r] * inv);
                }
        }
        __syncthreads();

        // ---- softsum chunk-partial (thread: k = t>>3, chunk c = t&7)
        {
            const int kk = t >> 3;
            const int c  = t & 7;
            const short8 v = *(const short8*)(PTp + kk * 128 + (((c ^ kk) & 7) << 4));
#pragma unroll
            for (int e = 0; e < 8; ++e) ss_acc += bf2f((unsigned short)v[e]);
        }

        // ---- agg MFMA: contraction n=64 (2 steps), A = XL rows d, B = PT rows k
#pragma unroll
        for (int kc = 0; kc < 2; ++kc) {
#pragma unroll
            for (int m = 0; m < 4; ++m) {
                const int d = w * 64 + m * 16 + lr;
                const int aC = kc * 4 + lg;
                const short8 afrag = *(const short8*)(XLp + d * 128 + (((aC ^ d) & 7) << 4));
#pragma unroll
                for (int kt = 0; kt < 4; ++kt) {
                    const int k = kt * 16 + lr;
                    const short8 bfrag = *(const short8*)(PTp + k * 128 + (((aC ^ k) & 7) << 4));
                    aacc[m][kt] = __builtin_amdgcn_mfma_f32_16x16x32_bf16(afrag, bfrag, aacc[m][kt], 0, 0, 0);
                }
            }
        }
        __syncthreads();   // XL/PT reads done before next tile restages
    }

    // ---- store agg partial: aggs[ns][b][d][k]
    float* ag = aggs + ((size_t)ns * B_ + b) * (D_ * K_);
#pragma unroll
    for (int m = 0; m < 4; ++m)
#pragma unroll
        for (int kt = 0; kt < 4; ++kt)
#pragma unroll
            for (int r = 0; r < 4; ++r)
                ag[(size_t)(w * 64 + m * 16 + lg * 4 + r) * K_ + kt * 16 + lr] = aacc[m][kt][r];

    // ---- store softsum partial: ssp[b][ns][k]
    ss_acc += __shfl_xor(ss_acc, 1);
    ss_acc += __shfl_xor(ss_acc, 2);
    ss_acc += __shfl_xor(ss_acc, 4);
    if ((t & 7) == 0) ssp[((size_t)b * 8 + ns) * K_ + (t >> 3)] = ss_acc;
}

// ---------------------------------------------------------------------------
// Kernel D1: vsum = sum_ns aggs - centers*softsum -> aggsum; partial sumsq -> nrmp
// ---------------------------------------------------------------------------
__global__ __launch_bounds__(256) void vlad_norm1(const float* __restrict__ aggs,
                                                  const float* __restrict__ centers,
                                                  const float* __restrict__ ssp,
                                                  float* __restrict__ aggsum,
                                                  float* __restrict__ nrmp) {
    const int ds = blockIdx.x;  // 0..7
    const int b  = blockIdx.y;
    const int t  = threadIdx.x;
    const int k  = t & 63;
    const int dg = t >> 6;

    __shared__ float red[4][64];

    float s0 = ssp[((size_t)b * 8 + dg) * K_ + k] + ssp[((size_t)b * 8 + dg + 4) * K_ + k];
    red[dg][k] = s0;
    __syncthreads();
    const float s = red[0][k] + red[1][k] + red[2][k] + red[3][k];
    __syncthreads();

    float sq = 0.f;
    for (int d = ds * 64 + dg; d < ds * 64 + 64; d += 4) {
        float v = -centers[d * K_ + k] * s;
#pragma unroll
        for (int i = 0; i < 8; ++i)
            v += aggs[((size_t)i * B_ + b) * (D_ * K_) + (size_t)d * K_ + k];
        aggsum[((size_t)b * D_ + d) * K_ + k] = v;
        sq = fmaf(v, v, sq);
    }
    red[dg][k] = sq;
    __syncthreads();
    if (t < 64) nrmp[((size_t)b * 8 + ds) * K_ + k] =
        red[0][k] + red[1][k] + red[2][k] + red[3][k];
}

// ---------------------------------------------------------------------------
// Kernel D2: finalize norms (intra-D + global L2), scale aggsum -> out
// ---------------------------------------------------------------------------
__global__ __launch_bounds__(256) void vlad_norm2(const float* __restrict__ aggsum,
                                                  const float* __restrict__ nrmp,
                                                  float* __restrict__ out) {
    const int ds = blockIdx.x;  // 0..7
    const int b  = blockIdx.y;
    const int t  = threadIdx.x;
    const int k  = t & 63;
    const int dg = t >> 6;

    __shared__ float inv1s[64];
    __shared__ float col2[64];
    __shared__ float inv2s;

    if (t < 64) {
        float tt = 0.f;
#pragma unroll
        for (int i = 0; i < 8; ++i) tt += nrmp[((size_t)b * 8 + i) * K_ + k];
        const float n1 = sqrtf(tt);
        const float i1 = 1.f / fmaxf(n1, 1e-12f);
        inv1s[k] = i1;
        const float c2 = n1 * i1;
        col2[k] = c2 * c2;
    }
    __syncthreads();
    if (t == 0) {
        float tt = 0.f;
        for (int kk = 0; kk < 64; ++kk) tt += col2[kk];
        inv2s = 1.f / fmaxf(sqrtf(tt), 1e-12f);
    }
    __syncthreads();
    const float i12 = inv1s[k] * inv2s;
    for (int d = ds * 64 + dg; d < ds * 64 + 64; d += 4)
        out[(size_t)b * (D_ * K_) + (size_t)d * K_ + k] =
            aggsum[((size_t)b * D_ + d) * K_ + k] * i12;
}

// ---------------------------------------------------------------------------
extern "C" void kernel_launch(void* const* d_in, const int* in_sizes, int n_in,
                              void* d_out, int out_size, void* d_ws, size_t ws_size,
                              hipStream_t stream) {
    const float* X       = (const float*)d_in[0];  // [B, D, N]
    const float* W       = (const float*)d_in[1];  // [K, D]
    const float* bias    = (const float*)d_in[2];  // [K]
    const float* centers = (const float*)d_in[3];  // [D, K]
    float* out = (float*)d_out;

    char* ws = (char*)d_ws;
    const size_t aggBytes = (size_t)B_ * D_ * K_ * sizeof(float);   // 4 MB
    float* aggs   = (float*)ws;                               // 8 x 4 MB
    float* aggsum = (float*)(ws + 8 * aggBytes);              // 4 MB
    float* ssp    = (float*)(ws + 9 * aggBytes);              // [B][8][K]
    float* nrmp   = (float*)(ws + 9 * aggBytes + 65536);      // [B][8][K]

    hipFuncSetAttribute((const void*)vlad_fused,
                        hipFuncAttributeMaxDynamicSharedMemorySize, SMEM_BYTES);

    vlad_fused<<<dim3(8, B_), 512, SMEM_BYTES, stream>>>(X, W, bias, aggs, ssp);
    vlad_norm1<<<dim3(8, B_), 256, 0, stream>>>(aggs, centers, ssp, aggsum, nrmp);
    vlad_norm2<<<dim3(8, B_), 256, 0, stream>>>(aggsum, nrmp, out);
}

// Round 8
// 87.127 us; speedup vs baseline: 9.5013x; 1.2480x over previous
//
#include <hip/hip_runtime.h>
#include <hip/hip_bf16.h>

#define B_ 32
#define D_ 512
#define K_ 64
#define N_ 4096

typedef __attribute__((ext_vector_type(8))) short short8;   // 8 bf16 (4 VGPRs)
typedef __attribute__((ext_vector_type(4))) short short4v;  // 4 bf16 (8 bytes)
typedef __attribute__((ext_vector_type(4))) float f32x4;

static __device__ __forceinline__ unsigned short f2bf(float f) {
    __hip_bfloat16 h = __float2bfloat16(f);
    return *reinterpret_cast<unsigned short*>(&h);
}
static __device__ __forceinline__ float bf2f(unsigned short u) {
    return __uint_as_float(((unsigned)u) << 16);
}

// LDS carve (bytes): WL 64K | XL 64K | XT 2x8K | PT 8K | sxc 1K (c,sum pairs)
#define SMEM_BYTES 156672
#define WL_OFF 0
#define XL_OFF 65536
#define XT_OFF 131072
#define PT_OFF 147456
#define SXC_OFF 155648

// ---------------------------------------------------------------------------
// Fused kernel (deep-pipelined): per n-tile of 64 -> scores MFMA -> softmax
// (single-barrier exact rescale) -> P in LDS -> agg MFMA (acc in VGPRs).
// X read from HBM exactly once. Load pipeline is 2 stages deep and crosses
// n-tile boundaries (stages 6,7 prefetch the next tile's chunks 0,1, staying
// in flight across softmax+agg). In-flight 32KB/CU > Little's-law 22KB.
// Block 512 thr (8 waves), 1 block/CU. Grid 8 ns x 32 b.
// ---------------------------------------------------------------------------
__global__ __launch_bounds__(512, 2) void vlad_fused(const float* __restrict__ X,
                                                     const float* __restrict__ W,
                                                     const float* __restrict__ bias,
                                                     float* __restrict__ aggs,
                                                     float* __restrict__ ssp) {
    extern __shared__ char smem[];
    char* WLp = smem + WL_OFF;
    char* XLp = smem + XL_OFF;
    char* XTp = smem + XT_OFF;
    char* PTp = smem + PT_OFF;
    float2* sxc = (float2*)(smem + SXC_OFF);   // [8 waves][16 lr] (c, sum)

    const int ns = blockIdx.x;   // 0..7  (n-range [ns*512, ns*512+512))
    const int b  = blockIdx.y;
    const int t  = threadIdx.x;
    const int w  = t >> 6;
    const int l  = t & 63;
    const int lg = l >> 4;
    const int lr = l & 15;
    const int strip = w & 3;
    const int khalf = w >> 2;

    // staging role: 2 d-rows x 4 n-cols per thread
    const int dq2 = t >> 4;   // 0..31 -> local d0 = dq2*2
    const int nq  = t & 15;   // n0 = nq*4
    const float* Xbase = X + (size_t)b * D_ * N_ + ns * 512 + nq * 4;

    // ---- issue first two X stages BEFORE W staging (in flight under it)
    float4 P0a, P0b, P1a, P1b;
    {
        const float* Xs = Xbase + (size_t)(dq2 * 2) * N_;          // (tile0, dsl0)
        P0a = *(const float4*)&Xs[0];
        P0b = *(const float4*)&Xs[N_];
        const float* Xs1 = Xbase + (size_t)(64 + dq2 * 2) * N_;    // (tile0, dsl1)
        P1a = *(const float4*)&Xs1[0];
        P1b = *(const float4*)&Xs1[N_];
    }

    // ---- stage full W -> WL [64 k][512 d] bf16, 1KB rows, XOR-swz (validated)
#pragma unroll 4
    for (int j = 0; j < 16; ++j) {
        const int idx = t + j * 512;       // f4 index over [64 k][128 f4]
        const int k = idx >> 7;
        const int cf = idx & 127;
        const float4 wv = *(const float4*)&W[k * D_ + cf * 4];
        const int C = cf >> 1;
        const int swz = (C & ~7) | ((C ^ k) & 7);
        short4v pk;
        pk[0] = (short)f2bf(wv.x); pk[1] = (short)f2bf(wv.y);
        pk[2] = (short)f2bf(wv.z); pk[3] = (short)f2bf(wv.w);
        *(short4v*)(WLp + k * 1024 + (swz << 4) + (cf & 1) * 8) = pk;
    }

    float bias_r[2][4];
#pragma unroll
    for (int ktl = 0; ktl < 2; ++ktl)
#pragma unroll
        for (int r = 0; r < 4; ++r)
            bias_r[ktl][r] = bias[khalf * 32 + ktl * 16 + lg * 4 + r];

    f32x4 aacc[4][4];
#pragma unroll
    for (int m = 0; m < 4; ++m)
#pragma unroll
        for (int kt = 0; kt < 4; ++kt) {
            aacc[m][kt][0] = 0.f; aacc[m][kt][1] = 0.f;
            aacc[m][kt][2] = 0.f; aacc[m][kt][3] = 0.f;
        }
    float ss_acc = 0.f;

    // write one staged 2x4 block into XL (row dglob0) + XT[buf] (transposed)
    auto stage_write = [&](int buf, int dglob0, const float4& r0, const float4& r1) {
        const float e0[4] = {r0.x, r0.y, r0.z, r0.w};
        const float e1[4] = {r1.x, r1.y, r1.z, r1.w};
        {
            short4v pk;
            pk[0] = (short)f2bf(e0[0]); pk[1] = (short)f2bf(e0[1]);
            pk[2] = (short)f2bf(e0[2]); pk[3] = (short)f2bf(e0[3]);
            const int d = dglob0;
            *(short4v*)(XLp + d * 128 + ((((nq >> 1) ^ d) & 7) << 4) + (nq & 1) * 8) = pk;
        }
        {
            short4v pk;
            pk[0] = (short)f2bf(e1[0]); pk[1] = (short)f2bf(e1[1]);
            pk[2] = (short)f2bf(e1[2]); pk[3] = (short)f2bf(e1[3]);
            const int d = dglob0 + 1;
            *(short4v*)(XLp + d * 128 + ((((nq >> 1) ^ d) & 7) << 4) + (nq & 1) * 8) = pk;
        }
#pragma unroll
        for (int c = 0; c < 4; ++c) {
            const int n = nq * 4 + c;
            const unsigned v = (unsigned)f2bf(e0[c]) | ((unsigned)f2bf(e1[c]) << 16);
            *(unsigned*)(XTp + buf * 8192 + n * 128 +
                         ((((dq2 >> 2) ^ n) & 7) << 4) + (dq2 & 3) * 4) = v;
        }
    };

    for (int nt = 0; nt < 8; ++nt) {
        // ---- tile prologue: write held stage (nt,0); A := data (nt,1)
        stage_write(0, dq2 * 2, P0a, P0b);
        __syncthreads();   // WL (first tile) + XT buf0 ready
        float4 Aa = P1a, Ab = P1b;

        f32x4 sacc[2];
#pragma unroll
        for (int ktl = 0; ktl < 2; ++ktl) {
            sacc[ktl][0] = 0.f; sacc[ktl][1] = 0.f; sacc[ktl][2] = 0.f; sacc[ktl][3] = 0.f;
        }

        for (int dsl = 0; dsl < 8; ++dsl) {
            // issue loads for stage s+2 (crosses into next tile at dsl 6,7)
            float4 Na, Nb;
            const int s2 = nt * 8 + dsl + 2;
            if (s2 < 64) {
                const int nt2 = s2 >> 3, d2 = s2 & 7;
                const float* Xs = Xbase + nt2 * 64 + (size_t)(d2 * 64 + dq2 * 2) * N_;
                Na = *(const float4*)&Xs[0];
                Nb = *(const float4*)&Xs[N_];
            }
            // MFMA scores on XT buf[dsl&1]
            const int cur = dsl & 1;
            const int n = strip * 16 + lr;
#pragma unroll
            for (int kc = 0; kc < 2; ++kc) {
                const int bC = kc * 4 + lg;
                const short8 bfrag = *(const short8*)(XTp + cur * 8192 + n * 128 +
                                                      (((bC ^ n) & 7) << 4));
#pragma unroll
                for (int ktl = 0; ktl < 2; ++ktl) {
                    const int k = khalf * 32 + ktl * 16 + lr;
                    const int aC = dsl * 8 + kc * 4 + lg;
                    const int swz = (aC & ~7) | ((aC ^ k) & 7);
                    const short8 afrag = *(const short8*)(WLp + k * 1024 + (swz << 4));
                    sacc[ktl] = __builtin_amdgcn_mfma_f32_16x16x32_bf16(afrag, bfrag, sacc[ktl], 0, 0, 0);
                }
            }
            if (dsl < 7) {
                // write A = data(stage nt*8+dsl+1): XT buf[(dsl+1)&1], XL rows (dsl+1)*64+...
                stage_write((dsl + 1) & 1, (dsl + 1) * 64 + dq2 * 2, Aa, Ab);
                Aa = Na; Ab = Nb;
                __syncthreads();
            } else {
                P0a = Aa; P0b = Ab;   // data (nt+1, 0)
                P1a = Na; P1b = Nb;   // data (nt+1, 1)
            }
        }

        // ---- softmax over k: wave-local shift c_w (exact: softmax shift-invariant),
        // single (c,sum) exchange with the partner k-half wave.
        float p[2][4];
        float cw = -1e30f;
#pragma unroll
        for (int ktl = 0; ktl < 2; ++ktl)
#pragma unroll
            for (int r = 0; r < 4; ++r) {
                p[ktl][r] = sacc[ktl][r] + bias_r[ktl][r];
                cw = fmaxf(cw, p[ktl][r]);
            }
        cw = fmaxf(cw, __shfl_xor(cw, 16));
        cw = fmaxf(cw, __shfl_xor(cw, 32));
        float sum = 0.f;
#pragma unroll
        for (int ktl = 0; ktl < 2; ++ktl)
#pragma unroll
            for (int r = 0; r < 4; ++r) { p[ktl][r] = __expf(p[ktl][r] - cw); sum += p[ktl][r]; }
        sum += __shfl_xor(sum, 16);
        sum += __shfl_xor(sum, 32);
        if (l < 16) sxc[w * 16 + lr] = make_float2(cw, sum);
        __syncthreads();
        const float2 other = sxc[(w ^ 4) * 16 + lr];
        const float cstar = fmaxf(cw, other.x);
        const float e_own = __expf(cw - cstar);
        const float e_oth = __expf(other.x - cstar);
        const float scale = e_own / (sum * e_own + other.y * e_oth);

        // ---- P tile -> LDS [64 k][64 n] bf16 (validated swizzle)
        {
            const int n = strip * 16 + lr;
#pragma unroll
            for (int ktl = 0; ktl < 2; ++ktl)
#pragma unroll
                for (int r = 0; r < 4; ++r) {
                    const int k = khalf * 32 + ktl * 16 + lg * 4 + r;
                    *(unsigned short*)(PTp + k * 128 + ((((n >> 3) ^ k) & 7) << 4) + (n & 7) * 2) =
                        f2bf(p[ktl][r] * scale);
                }
        }
        __syncthreads();

        // ---- softsum chunk-partial (thread: k = t>>3, chunk c = t&7)
        {
            const int kk = t >> 3;
            const int c  = t & 7;
            const short8 v = *(const short8*)(PTp + kk * 128 + (((c ^ kk) & 7) << 4));
#pragma unroll
            for (int e = 0; e < 8; ++e) ss_acc += bf2f((unsigned short)v[e]);
        }

        // ---- agg MFMA: contraction n=64 (2 steps), A = XL rows d, B = PT rows k
#pragma unroll
        for (int kc = 0; kc < 2; ++kc) {
#pragma unroll
            for (int m = 0; m < 4; ++m) {
                const int d = w * 64 + m * 16 + lr;
                const int aC = kc * 4 + lg;
                const short8 afrag = *(const short8*)(XLp + d * 128 + (((aC ^ d) & 7) << 4));
#pragma unroll
                for (int kt = 0; kt < 4; ++kt) {
                    const int k = kt * 16 + lr;
                    const short8 bfrag = *(const short8*)(PTp + k * 128 + (((aC ^ k) & 7) << 4));
                    aacc[m][kt] = __builtin_amdgcn_mfma_f32_16x16x32_bf16(afrag, bfrag, aacc[m][kt], 0, 0, 0);
                }
            }
        }
        __syncthreads();   // XL/PT reads done before next tile restages
    }

    // ---- store agg partial: aggs[ns][b][d][k]
    float* ag = aggs + ((size_t)ns * B_ + b) * (D_ * K_);
#pragma unroll
    for (int m = 0; m < 4; ++m)
#pragma unroll
        for (int kt = 0; kt < 4; ++kt)
#pragma unroll
            for (int r = 0; r < 4; ++r)
                ag[(size_t)(w * 64 + m * 16 + lg * 4 + r) * K_ + kt * 16 + lr] = aacc[m][kt][r];

    // ---- store softsum partial: ssp[b][ns][k]
    ss_acc += __shfl_xor(ss_acc, 1);
    ss_acc += __shfl_xor(ss_acc, 2);
    ss_acc += __shfl_xor(ss_acc, 4);
    if ((t & 7) == 0) ssp[((size_t)b * 8 + ns) * K_ + (t >> 3)] = ss_acc;
}

// ---------------------------------------------------------------------------
// Kernel D1: vsum = sum_ns aggs - centers*softsum -> aggsum; partial sumsq -> nrmp
// ---------------------------------------------------------------------------
__global__ __launch_bounds__(256) void vlad_norm1(const float* __restrict__ aggs,
                                                  const float* __restrict__ centers,
                                                  const float* __restrict__ ssp,
                                                  float* __restrict__ aggsum,
                                                  float* __restrict__ nrmp) {
    const int ds = blockIdx.x;  // 0..7
    const int b  = blockIdx.y;
    const int t  = threadIdx.x;
    const int k  = t & 63;
    const int dg = t >> 6;

    __shared__ float red[4][64];

    float s0 = ssp[((size_t)b * 8 + dg) * K_ + k] + ssp[((size_t)b * 8 + dg + 4) * K_ + k];
    red[dg][k] = s0;
    __syncthreads();
    const float s = red[0][k] + red[1][k] + red[2][k] + red[3][k];
    __syncthreads();

    float sq = 0.f;
    for (int d = ds * 64 + dg; d < ds * 64 + 64; d += 4) {
        float v = -centers[d * K_ + k] * s;
#pragma unroll
        for (int i = 0; i < 8; ++i)
            v += aggs[((size_t)i * B_ + b) * (D_ * K_) + (size_t)d * K_ + k];
        aggsum[((size_t)b * D_ + d) * K_ + k] = v;
        sq = fmaf(v, v, sq);
    }
    red[dg][k] = sq;
    __syncthreads();
    if (t < 64) nrmp[((size_t)b * 8 + ds) * K_ + k] =
        red[0][k] + red[1][k] + red[2][k] + red[3][k];
}

// ---------------------------------------------------------------------------
// Kernel D2: finalize norms (intra-D + global L2), scale aggsum -> out
// ---------------------------------------------------------------------------
__global__ __launch_bounds__(256) void vlad_norm2(const float* __restrict__ aggsum,
                                                  const float* __restrict__ nrmp,
                                                  float* __restrict__ out) {
    const int ds = blockIdx.x;  // 0..7
    const int b  = blockIdx.y;
    const int t  = threadIdx.x;
    const int k  = t & 63;
    const int dg = t >> 6;

    __shared__ float inv1s[64];
    __shared__ float col2[64];
    __shared__ float inv2s;

    if (t < 64) {
        float tt = 0.f;
#pragma unroll
        for (int i = 0; i < 8; ++i) tt += nrmp[((size_t)b * 8 + i) * K_ + k];
        const float n1 = sqrtf(tt);
        const float i1 = 1.f / fmaxf(n1, 1e-12f);
        inv1s[k] = i1;
        const float c2 = n1 * i1;
        col2[k] = c2 * c2;
    }
    __syncthreads();
    if (t == 0) {
        float tt = 0.f;
        for (int kk = 0; kk < 64; ++kk) tt += col2[kk];
        inv2s = 1.f / fmaxf(sqrtf(tt), 1e-12f);
    }
    __syncthreads();
    const float i12 = inv1s[k] * inv2s;
    for (int d = ds * 64 + dg; d < ds * 64 + 64; d += 4)
        out[(size_t)b * (D_ * K_) + (size_t)d * K_ + k] =
            aggsum[((size_t)b * D_ + d) * K_ + k] * i12;
}

// ---------------------------------------------------------------------------
extern "C" void kernel_launch(void* const* d_in, const int* in_sizes, int n_in,
                              void* d_out, int out_size, void* d_ws, size_t ws_size,
                              hipStream_t stream) {
    const float* X       = (const float*)d_in[0];  // [B, D, N]
    const float* W       = (const float*)d_in[1];  // [K, D]
    const float* bias    = (const float*)d_in[2];  // [K]
    const float* centers = (const float*)d_in[3];  // [D, K]
    float* out = (float*)d_out;

    char* ws = (char*)d_ws;
    const size_t aggBytes = (size_t)B_ * D_ * K_ * sizeof(float);   // 4 MB
    float* aggs   = (float*)ws;                               // 8 x 4 MB
    float* aggsum = (float*)(ws + 8 * aggBytes);              // 4 MB
    float* ssp    = (float*)(ws + 9 * aggBytes);              // [B][8][K]
    float* nrmp   = (float*)(ws + 9 * aggBytes + 65536);      // [B][8][K]

    hipFuncSetAttribute((const void*)vlad_fused,
                        hipFuncAttributeMaxDynamicSharedMemorySize, SMEM_BYTES);

    vlad_fused<<<dim3(8, B_), 512, SMEM_BYTES, stream>>>(X, W, bias, aggs, ssp);
    vlad_norm1<<<dim3(8, B_), 256, 0, stream>>>(aggs, centers, ssp, aggsum, nrmp);
    vlad_norm2<<<dim3(8, B_), 256, 0, stream>>>(aggsum, nrmp, out);
}

// Round 9
// 86.409 us; speedup vs baseline: 9.5803x; 1.0083x over previous
//
#include <hip/hip_runtime.h>
#include <hip/hip_bf16.h>

#define B_ 32
#define D_ 512
#define K_ 64
#define N_ 4096

typedef __attribute__((ext_vector_type(8))) short short8;   // 8 bf16 (4 VGPRs)
typedef __attribute__((ext_vector_type(4))) short short4v;  // 4 bf16 (8 bytes)
typedef __attribute__((ext_vector_type(4))) float f32x4;

static __device__ __forceinline__ unsigned short f2bf(float f) {
    __hip_bfloat16 h = __float2bfloat16(f);
    return *reinterpret_cast<unsigned short*>(&h);
}
static __device__ __forceinline__ float bf2f(unsigned short u) {
    return __uint_as_float(((unsigned)u) << 16);
}

// LDS carve (bytes): WL 64K | XL 64K | XT 2x8K | PT 8K | sxc 1K (c,sum pairs)
#define SMEM_BYTES 156672
#define WL_OFF 0
#define XL_OFF 65536
#define XT_OFF 131072
#define PT_OFF 147456
#define SXC_OFF 155648

// ---------------------------------------------------------------------------
// Fused kernel, 4-deep register prefetch (PD=4): per stage {write slot ->
// barrier -> issue load s+4 -> 4 MFMAs}. At every tile's softmax/agg tail the
// 4 slots hold the NEXT tile's stages 0-3 (64KB/CU in flight, drains ~6400cyc
// at BW share) so HBM stays busy through the ~1500cyc non-load phase.
// X read from HBM exactly once; P never goes to global.
// Block 512 thr (8 waves), 1 block/CU. Grid 8 ns x 32 b.
// ---------------------------------------------------------------------------
__global__ __launch_bounds__(512, 2) void vlad_fused(const float* __restrict__ X,
                                                     const float* __restrict__ W,
                                                     const float* __restrict__ bias,
                                                     float* __restrict__ aggs,
                                                     float* __restrict__ ssp) {
    extern __shared__ char smem[];
    char* WLp = smem + WL_OFF;
    char* XLp = smem + XL_OFF;
    char* XTp = smem + XT_OFF;
    char* PTp = smem + PT_OFF;
    float2* sxc = (float2*)(smem + SXC_OFF);   // [8 waves][16 lr] (c, sum)

    const int ns = blockIdx.x;   // 0..7  (n-range [ns*512, ns*512+512))
    const int b  = blockIdx.y;
    const int t  = threadIdx.x;
    const int w  = t >> 6;
    const int l  = t & 63;
    const int lg = l >> 4;
    const int lr = l & 15;
    const int strip = w & 3;
    const int khalf = w >> 2;

    // staging role: 2 d-rows x 4 n-cols per thread
    const int dq2 = t >> 4;   // 0..31 -> local d0 = dq2*2
    const int nq  = t & 15;   // n0 = nq*4
    const float* Xbase = X + (size_t)b * D_ * N_ + ns * 512 + nq * 4;

    // ---- prefetch slots (statically indexed via unrolled dsl: slot = dsl&3)
    float4 Sa[4], Sb[4];
#pragma unroll
    for (int s = 0; s < 4; ++s) {   // stages 0..3 of tile 0
        const float* Xs = Xbase + (size_t)(s * 64 + dq2 * 2) * N_;
        Sa[s] = *(const float4*)&Xs[0];
        Sb[s] = *(const float4*)&Xs[N_];
    }

    // ---- stage full W -> WL [64 k][512 d] bf16, 1KB rows, XOR-swz (validated)
#pragma unroll 4
    for (int j = 0; j < 16; ++j) {
        const int idx = t + j * 512;       // f4 index over [64 k][128 f4]
        const int k = idx >> 7;
        const int cf = idx & 127;
        const float4 wv = *(const float4*)&W[k * D_ + cf * 4];
        const int C = cf >> 1;
        const int swz = (C & ~7) | ((C ^ k) & 7);
        short4v pk;
        pk[0] = (short)f2bf(wv.x); pk[1] = (short)f2bf(wv.y);
        pk[2] = (short)f2bf(wv.z); pk[3] = (short)f2bf(wv.w);
        *(short4v*)(WLp + k * 1024 + (swz << 4) + (cf & 1) * 8) = pk;
    }

    float bias_r[2][4];
#pragma unroll
    for (int ktl = 0; ktl < 2; ++ktl)
#pragma unroll
        for (int r = 0; r < 4; ++r)
            bias_r[ktl][r] = bias[khalf * 32 + ktl * 16 + lg * 4 + r];

    f32x4 aacc[4][4];
#pragma unroll
    for (int m = 0; m < 4; ++m)
#pragma unroll
        for (int kt = 0; kt < 4; ++kt) {
            aacc[m][kt][0] = 0.f; aacc[m][kt][1] = 0.f;
            aacc[m][kt][2] = 0.f; aacc[m][kt][3] = 0.f;
        }
    float ss_acc = 0.f;

    // write one staged 2x4 block into XL (row dglob0) + XT[buf] (transposed)
    auto stage_write = [&](int buf, int dglob0, const float4& r0, const float4& r1) {
        const float e0[4] = {r0.x, r0.y, r0.z, r0.w};
        const float e1[4] = {r1.x, r1.y, r1.z, r1.w};
        {
            short4v pk;
            pk[0] = (short)f2bf(e0[0]); pk[1] = (short)f2bf(e0[1]);
            pk[2] = (short)f2bf(e0[2]); pk[3] = (short)f2bf(e0[3]);
            const int d = dglob0;
            *(short4v*)(XLp + d * 128 + ((((nq >> 1) ^ d) & 7) << 4) + (nq & 1) * 8) = pk;
        }
        {
            short4v pk;
            pk[0] = (short)f2bf(e1[0]); pk[1] = (short)f2bf(e1[1]);
            pk[2] = (short)f2bf(e1[2]); pk[3] = (short)f2bf(e1[3]);
            const int d = dglob0 + 1;
            *(short4v*)(XLp + d * 128 + ((((nq >> 1) ^ d) & 7) << 4) + (nq & 1) * 8) = pk;
        }
#pragma unroll
        for (int c = 0; c < 4; ++c) {
            const int n = nq * 4 + c;
            const unsigned v = (unsigned)f2bf(e0[c]) | ((unsigned)f2bf(e1[c]) << 16);
            *(unsigned*)(XTp + buf * 8192 + n * 128 +
                         ((((dq2 >> 2) ^ n) & 7) << 4) + (dq2 & 3) * 4) = v;
        }
    };

    __syncthreads();   // WL ready (XT/XL writes all happen after stage barriers)

    for (int nt = 0; nt < 8; ++nt) {
        f32x4 sacc[2];
#pragma unroll
        for (int ktl = 0; ktl < 2; ++ktl) {
            sacc[ktl][0] = 0.f; sacc[ktl][1] = 0.f; sacc[ktl][2] = 0.f; sacc[ktl][3] = 0.f;
        }

#pragma unroll
        for (int dsl = 0; dsl < 8; ++dsl) {
            const int slot = dsl & 3;       // static (full unroll)
            const int cur  = dsl & 1;
            // write this stage's data (loaded 4 stages ago)
            stage_write(cur, dsl * 64 + dq2 * 2, Sa[slot], Sb[slot]);
            __syncthreads();
            // refill the slot: stage s+4 (crosses into next tile at dsl>=4)
            const int s4 = nt * 8 + dsl + 4;
            if (s4 < 64) {
                const int nt2 = s4 >> 3, d2 = s4 & 7;
                const float* Xs = Xbase + nt2 * 64 + (size_t)(d2 * 64 + dq2 * 2) * N_;
                Sa[slot] = *(const float4*)&Xs[0];
                Sb[slot] = *(const float4*)&Xs[N_];
            }
            // MFMA scores on XT buf[cur]
            const int n = strip * 16 + lr;
#pragma unroll
            for (int kc = 0; kc < 2; ++kc) {
                const int bC = kc * 4 + lg;
                const short8 bfrag = *(const short8*)(XTp + cur * 8192 + n * 128 +
                                                      (((bC ^ n) & 7) << 4));
#pragma unroll
                for (int ktl = 0; ktl < 2; ++ktl) {
                    const int k = khalf * 32 + ktl * 16 + lr;
                    const int aC = dsl * 8 + kc * 4 + lg;
                    const int swz = (aC & ~7) | ((aC ^ k) & 7);
                    const short8 afrag = *(const short8*)(WLp + k * 1024 + (swz << 4));
                    sacc[ktl] = __builtin_amdgcn_mfma_f32_16x16x32_bf16(afrag, bfrag, sacc[ktl], 0, 0, 0);
                }
            }
        }

        // ---- softmax over k: wave-local shift (exact), single (c,sum) exchange
        float p[2][4];
        float cw = -1e30f;
#pragma unroll
        for (int ktl = 0; ktl < 2; ++ktl)
#pragma unroll
            for (int r = 0; r < 4; ++r) {
                p[ktl][r] = sacc[ktl][r] + bias_r[ktl][r];
                cw = fmaxf(cw, p[ktl][r]);
            }
        cw = fmaxf(cw, __shfl_xor(cw, 16));
        cw = fmaxf(cw, __shfl_xor(cw, 32));
        float sum = 0.f;
#pragma unroll
        for (int ktl = 0; ktl < 2; ++ktl)
#pragma unroll
            for (int r = 0; r < 4; ++r) { p[ktl][r] = __expf(p[ktl][r] - cw); sum += p[ktl][r]; }
        sum += __shfl_xor(sum, 16);
        sum += __shfl_xor(sum, 32);
        if (l < 16) sxc[w * 16 + lr] = make_float2(cw, sum);
        __syncthreads();
        const float2 other = sxc[(w ^ 4) * 16 + lr];
        const float cstar = fmaxf(cw, other.x);
        const float e_own = __expf(cw - cstar);
        const float e_oth = __expf(other.x - cstar);
        const float scale = e_own / (sum * e_own + other.y * e_oth);

        // ---- P tile -> LDS [64 k][64 n] bf16 (validated swizzle)
        {
            const int n = strip * 16 + lr;
#pragma unroll
            for (int ktl = 0; ktl < 2; ++ktl)
#pragma unroll
                for (int r = 0; r < 4; ++r) {
                    const int k = khalf * 32 + ktl * 16 + lg * 4 + r;
                    *(unsigned short*)(PTp + k * 128 + ((((n >> 3) ^ k) & 7) << 4) + (n & 7) * 2) =
                        f2bf(p[ktl][r] * scale);
                }
        }
        __syncthreads();

        // ---- softsum chunk-partial (thread: k = t>>3, chunk c = t&7)
        {
            const int kk = t >> 3;
            const int c  = t & 7;
            const short8 v = *(const short8*)(PTp + kk * 128 + (((c ^ kk) & 7) << 4));
#pragma unroll
            for (int e = 0; e < 8; ++e) ss_acc += bf2f((unsigned short)v[e]);
        }

        // ---- agg MFMA: contraction n=64 (2 steps), A = XL rows d, B = PT rows k
#pragma unroll
        for (int kc = 0; kc < 2; ++kc) {
#pragma unroll
            for (int m = 0; m < 4; ++m) {
                const int d = w * 64 + m * 16 + lr;
                const int aC = kc * 4 + lg;
                const short8 afrag = *(const short8*)(XLp + d * 128 + (((aC ^ d) & 7) << 4));
#pragma unroll
                for (int kt = 0; kt < 4; ++kt) {
                    const int k = kt * 16 + lr;
                    const short8 bfrag = *(const short8*)(PTp + k * 128 + (((aC ^ k) & 7) << 4));
                    aacc[m][kt] = __builtin_amdgcn_mfma_f32_16x16x32_bf16(afrag, bfrag, aacc[m][kt], 0, 0, 0);
                }
            }
        }
        __syncthreads();   // XL/PT reads done before next tile restages
    }

    // ---- store agg partial: aggs[ns][b][d][k]
    float* ag = aggs + ((size_t)ns * B_ + b) * (D_ * K_);
#pragma unroll
    for (int m = 0; m < 4; ++m)
#pragma unroll
        for (int kt = 0; kt < 4; ++kt)
#pragma unroll
            for (int r = 0; r < 4; ++r)
                ag[(size_t)(w * 64 + m * 16 + lg * 4 + r) * K_ + kt * 16 + lr] = aacc[m][kt][r];

    // ---- store softsum partial: ssp[b][ns][k]
    ss_acc += __shfl_xor(ss_acc, 1);
    ss_acc += __shfl_xor(ss_acc, 2);
    ss_acc += __shfl_xor(ss_acc, 4);
    if ((t & 7) == 0) ssp[((size_t)b * 8 + ns) * K_ + (t >> 3)] = ss_acc;
}

// ---------------------------------------------------------------------------
// Kernel D1: vsum = sum_ns aggs - centers*softsum -> aggsum; partial sumsq -> nrmp
// ---------------------------------------------------------------------------
__global__ __launch_bounds__(256) void vlad_norm1(const float* __restrict__ aggs,
                                                  const float* __restrict__ centers,
                                                  const float* __restrict__ ssp,
                                                  float* __restrict__ aggsum,
                                                  float* __restrict__ nrmp) {
    const int ds = blockIdx.x;  // 0..7
    const int b  = blockIdx.y;
    const int t  = threadIdx.x;
    const int k  = t & 63;
    const int dg = t >> 6;

    __shared__ float red[4][64];

    float s0 = ssp[((size_t)b * 8 + dg) * K_ + k] + ssp[((size_t)b * 8 + dg + 4) * K_ + k];
    red[dg][k] = s0;
    __syncthreads();
    const float s = red[0][k] + red[1][k] + red[2][k] + red[3][k];
    __syncthreads();

    float sq = 0.f;
    for (int d = ds * 64 + dg; d < ds * 64 + 64; d += 4) {
        float v = -centers[d * K_ + k] * s;
#pragma unroll
        for (int i = 0; i < 8; ++i)
            v += aggs[((size_t)i * B_ + b) * (D_ * K_) + (size_t)d * K_ + k];
        aggsum[((size_t)b * D_ + d) * K_ + k] = v;
        sq = fmaf(v, v, sq);
    }
    red[dg][k] = sq;
    __syncthreads();
    if (t < 64) nrmp[((size_t)b * 8 + ds) * K_ + k] =
        red[0][k] + red[1][k] + red[2][k] + red[3][k];
}

// ---------------------------------------------------------------------------
// Kernel D2: finalize norms (intra-D + global L2), scale aggsum -> out
// ---------------------------------------------------------------------------
__global__ __launch_bounds__(256) void vlad_norm2(const float* __restrict__ aggsum,
                                                  const float* __restrict__ nrmp,
                                                  float* __restrict__ out) {
    const int ds = blockIdx.x;  // 0..7
    const int b  = blockIdx.y;
    const int t  = threadIdx.x;
    const int k  = t & 63;
    const int dg = t >> 6;

    __shared__ float inv1s[64];
    __shared__ float col2[64];
    __shared__ float inv2s;

    if (t < 64) {
        float tt = 0.f;
#pragma unroll
        for (int i = 0; i < 8; ++i) tt += nrmp[((size_t)b * 8 + i) * K_ + k];
        const float n1 = sqrtf(tt);
        const float i1 = 1.f / fmaxf(n1, 1e-12f);
        inv1s[k] = i1;
        const float c2 = n1 * i1;
        col2[k] = c2 * c2;
    }
    __syncthreads();
    if (t == 0) {
        float tt = 0.f;
        for (int kk = 0; kk < 64; ++kk) tt += col2[kk];
        inv2s = 1.f / fmaxf(sqrtf(tt), 1e-12f);
    }
    __syncthreads();
    const float i12 = inv1s[k] * inv2s;
    for (int d = ds * 64 + dg; d < ds * 64 + 64; d += 4)
        out[(size_t)b * (D_ * K_) + (size_t)d * K_ + k] =
            aggsum[((size_t)b * D_ + d) * K_ + k] * i12;
}

// ---------------------------------------------------------------------------
extern "C" void kernel_launch(void* const* d_in, const int* in_sizes, int n_in,
                              void* d_out, int out_size, void* d_ws, size_t ws_size,
                              hipStream_t stream) {
    const float* X       = (const float*)d_in[0];  // [B, D, N]
    const float* W       = (const float*)d_in[1];  // [K, D]
    const float* bias    = (const float*)d_in[2];  // [K]
    const float* centers = (const float*)d_in[3];  // [D, K]
    float* out = (float*)d_out;

    char* ws = (char*)d_ws;
    const size_t aggBytes = (size_t)B_ * D_ * K_ * sizeof(float);   // 4 MB
    float* aggs   = (float*)ws;                               // 8 x 4 MB
    float* aggsum = (float*)(ws + 8 * aggBytes);              // 4 MB
    float* ssp    = (float*)(ws + 9 * aggBytes);              // [B][8][K]
    float* nrmp   = (float*)(ws + 9 * aggBytes + 65536);      // [B][8][K]

    hipFuncSetAttribute((const void*)vlad_fused,
                        hipFuncAttributeMaxDynamicSharedMemorySize, SMEM_BYTES);

    vlad_fused<<<dim3(8, B_), 512, SMEM_BYTES, stream>>>(X, W, bias, aggs, ssp);
    vlad_norm1<<<dim3(8, B_), 256, 0, stream>>>(aggs, centers, ssp, aggsum, nrmp);
    vlad_norm2<<<dim3(8, B_), 256, 0, stream>>>(aggsum, nrmp, out);
}

// Round 10
// 85.444 us; speedup vs baseline: 9.6884x; 1.0113x over previous
//
#include <hip/hip_runtime.h>
#include <hip/hip_bf16.h>

#define B_ 32
#define D_ 512
#define K_ 64
#define N_ 4096

typedef __attribute__((ext_vector_type(8))) short short8;   // 8 bf16 (4 VGPRs)
typedef __attribute__((ext_vector_type(4))) short short4v;  // 4 bf16 (8 bytes)
typedef __attribute__((ext_vector_type(4))) float f32x4;

static __device__ __forceinline__ unsigned short f2bf(float f) {
    __hip_bfloat16 h = __float2bfloat16(f);
    return *reinterpret_cast<unsigned short*>(&h);
}
static __device__ __forceinline__ float bf2f(unsigned short u) {
    return __uint_as_float(((unsigned)u) << 16);
}
// 16B LDS read as two 8B reads (rows are 8B-aligned due to +8B padding)
static __device__ __forceinline__ short8 lds_read16(const char* p) {
    const short4v lo = *(const short4v*)p;
    const short4v hi = *(const short4v*)(p + 8);
    short8 r;
    r[0] = lo[0]; r[1] = lo[1]; r[2] = lo[2]; r[3] = lo[3];
    r[4] = hi[0]; r[5] = hi[1]; r[6] = hi[2]; r[7] = hi[3];
    return r;
}

// Row strides padded +8B: row*stride/4 % 32 = 2*row -> bank start spreads with
// lane's row (lr), killing the 8-way "row stride = multiple of 128B" conflicts.
#define WSTR 1032   // WL row (was 1024)
#define TSTR 136    // XL/XT/PT row (was 128)
#define XTBUF 8704  // 64*136

// LDS carve (bytes): WL 66048 | XL 69632 | XT 2x8704 | PT 8704 | sxc 1024
#define SMEM_BYTES 162816
#define WL_OFF 0
#define XL_OFF 66048
#define XT_OFF 135680
#define PT_OFF 153088
#define SXC_OFF 161792

// ---------------------------------------------------------------------------
// Fused kernel (padded-LDS): per n-tile of 64 -> scores MFMA -> softmax
// (single-barrier exact rescale) -> P in LDS -> agg MFMA (acc in VGPRs).
// X read from HBM exactly once; P never goes to global. 4-deep reg prefetch.
// Block 512 thr (8 waves), 1 block/CU. Grid 8 ns x 32 b.
// ---------------------------------------------------------------------------
__global__ __launch_bounds__(512, 2) void vlad_fused(const float* __restrict__ X,
                                                     const float* __restrict__ W,
                                                     const float* __restrict__ bias,
                                                     float* __restrict__ aggs,
                                                     float* __restrict__ ssp) {
    extern __shared__ char smem[];
    char* WLp = smem + WL_OFF;
    char* XLp = smem + XL_OFF;
    char* XTp = smem + XT_OFF;
    char* PTp = smem + PT_OFF;
    float2* sxc = (float2*)(smem + SXC_OFF);   // [8 waves][16 lr] (c, sum)

    const int ns = blockIdx.x;   // 0..7  (n-range [ns*512, ns*512+512))
    const int b  = blockIdx.y;
    const int t  = threadIdx.x;
    const int w  = t >> 6;
    const int l  = t & 63;
    const int lg = l >> 4;
    const int lr = l & 15;
    const int strip = w & 3;
    const int khalf = w >> 2;

    // staging role: 2 d-rows x 4 n-cols per thread
    const int dq2 = t >> 4;   // 0..31 -> local d0 = dq2*2
    const int nq  = t & 15;   // n0 = nq*4
    const float* Xbase = X + (size_t)b * D_ * N_ + ns * 512 + nq * 4;

    // ---- prefetch slots (statically indexed via unrolled dsl: slot = dsl&3)
    float4 Sa[4], Sb[4];
#pragma unroll
    for (int s = 0; s < 4; ++s) {   // stages 0..3 of tile 0
        const float* Xs = Xbase + (size_t)(s * 64 + dq2 * 2) * N_;
        Sa[s] = *(const float4*)&Xs[0];
        Sb[s] = *(const float4*)&Xs[N_];
    }

    // ---- stage full W -> WL [64 k][512 d] bf16, padded rows, XOR-swz
#pragma unroll 4
    for (int j = 0; j < 16; ++j) {
        const int idx = t + j * 512;       // f4 index over [64 k][128 f4]
        const int k = idx >> 7;
        const int cf = idx & 127;
        const float4 wv = *(const float4*)&W[k * D_ + cf * 4];
        const int C = cf >> 1;
        const int swz = (C & ~7) | ((C ^ k) & 7);
        short4v pk;
        pk[0] = (short)f2bf(wv.x); pk[1] = (short)f2bf(wv.y);
        pk[2] = (short)f2bf(wv.z); pk[3] = (short)f2bf(wv.w);
        *(short4v*)(WLp + k * WSTR + (swz << 4) + (cf & 1) * 8) = pk;
    }

    float bias_r[2][4];
#pragma unroll
    for (int ktl = 0; ktl < 2; ++ktl)
#pragma unroll
        for (int r = 0; r < 4; ++r)
            bias_r[ktl][r] = bias[khalf * 32 + ktl * 16 + lg * 4 + r];

    f32x4 aacc[4][4];
#pragma unroll
    for (int m = 0; m < 4; ++m)
#pragma unroll
        for (int kt = 0; kt < 4; ++kt) {
            aacc[m][kt][0] = 0.f; aacc[m][kt][1] = 0.f;
            aacc[m][kt][2] = 0.f; aacc[m][kt][3] = 0.f;
        }
    float ss_acc = 0.f;

    // write one staged 2x4 block into XL (row dglob0) + XT[buf] (transposed)
    auto stage_write = [&](int buf, int dglob0, const float4& r0, const float4& r1) {
        const float e0[4] = {r0.x, r0.y, r0.z, r0.w};
        const float e1[4] = {r1.x, r1.y, r1.z, r1.w};
        {
            short4v pk;
            pk[0] = (short)f2bf(e0[0]); pk[1] = (short)f2bf(e0[1]);
            pk[2] = (short)f2bf(e0[2]); pk[3] = (short)f2bf(e0[3]);
            const int d = dglob0;
            *(short4v*)(XLp + d * TSTR + ((((nq >> 1) ^ d) & 7) << 4) + (nq & 1) * 8) = pk;
        }
        {
            short4v pk;
            pk[0] = (short)f2bf(e1[0]); pk[1] = (short)f2bf(e1[1]);
            pk[2] = (short)f2bf(e1[2]); pk[3] = (short)f2bf(e1[3]);
            const int d = dglob0 + 1;
            *(short4v*)(XLp + d * TSTR + ((((nq >> 1) ^ d) & 7) << 4) + (nq & 1) * 8) = pk;
        }
#pragma unroll
        for (int c = 0; c < 4; ++c) {
            const int n = nq * 4 + c;
            const unsigned v = (unsigned)f2bf(e0[c]) | ((unsigned)f2bf(e1[c]) << 16);
            *(unsigned*)(XTp + buf * XTBUF + n * TSTR +
                         ((((dq2 >> 2) ^ n) & 7) << 4) + (dq2 & 3) * 4) = v;
        }
    };

    __syncthreads();   // WL ready (XT/XL writes all happen after stage barriers)

    for (int nt = 0; nt < 8; ++nt) {
        f32x4 sacc[2];
#pragma unroll
        for (int ktl = 0; ktl < 2; ++ktl) {
            sacc[ktl][0] = 0.f; sacc[ktl][1] = 0.f; sacc[ktl][2] = 0.f; sacc[ktl][3] = 0.f;
        }

#pragma unroll
        for (int dsl = 0; dsl < 8; ++dsl) {
            const int slot = dsl & 3;       // static (full unroll)
            const int cur  = dsl & 1;
            // write this stage's data (loaded 4 stages ago)
            stage_write(cur, dsl * 64 + dq2 * 2, Sa[slot], Sb[slot]);
            __syncthreads();
            // refill the slot: stage s+4 (crosses into next tile at dsl>=4)
            const int s4 = nt * 8 + dsl + 4;
            if (s4 < 64) {
                const int nt2 = s4 >> 3, d2 = s4 & 7;
                const float* Xs = Xbase + nt2 * 64 + (size_t)(d2 * 64 + dq2 * 2) * N_;
                Sa[slot] = *(const float4*)&Xs[0];
                Sb[slot] = *(const float4*)&Xs[N_];
            }
            // MFMA scores on XT buf[cur]
            const int n = strip * 16 + lr;
#pragma unroll
            for (int kc = 0; kc < 2; ++kc) {
                const int bC = kc * 4 + lg;
                const short8 bfrag = lds_read16(XTp + cur * XTBUF + n * TSTR +
                                                (((bC ^ n) & 7) << 4));
#pragma unroll
                for (int ktl = 0; ktl < 2; ++ktl) {
                    const int k = khalf * 32 + ktl * 16 + lr;
                    const int aC = dsl * 8 + kc * 4 + lg;
                    const int swz = (aC & ~7) | ((aC ^ k) & 7);
                    const short8 afrag = lds_read16(WLp + k * WSTR + (swz << 4));
                    sacc[ktl] = __builtin_amdgcn_mfma_f32_16x16x32_bf16(afrag, bfrag, sacc[ktl], 0, 0, 0);
                }
            }
        }

        // ---- softmax over k: wave-local shift (exact), single (c,sum) exchange
        float p[2][4];
        float cw = -1e30f;
#pragma unroll
        for (int ktl = 0; ktl < 2; ++ktl)
#pragma unroll
            for (int r = 0; r < 4; ++r) {
                p[ktl][r] = sacc[ktl][r] + bias_r[ktl][r];
                cw = fmaxf(cw, p[ktl][r]);
            }
        cw = fmaxf(cw, __shfl_xor(cw, 16));
        cw = fmaxf(cw, __shfl_xor(cw, 32));
        float sum = 0.f;
#pragma unroll
        for (int ktl = 0; ktl < 2; ++ktl)
#pragma unroll
            for (int r = 0; r < 4; ++r) { p[ktl][r] = __expf(p[ktl][r] - cw); sum += p[ktl][r]; }
        sum += __shfl_xor(sum, 16);
        sum += __shfl_xor(sum, 32);
        if (l < 16) sxc[w * 16 + lr] = make_float2(cw, sum);
        __syncthreads();
        const float2 other = sxc[(w ^ 4) * 16 + lr];
        const float cstar = fmaxf(cw, other.x);
        const float e_own = __expf(cw - cstar);
        const float e_oth = __expf(other.x - cstar);
        const float scale = e_own / (sum * e_own + other.y * e_oth);

        // ---- P tile -> LDS [64 k][64 n] bf16 (padded rows, XOR-swz)
        {
            const int n = strip * 16 + lr;
#pragma unroll
            for (int ktl = 0; ktl < 2; ++ktl)
#pragma unroll
                for (int r = 0; r < 4; ++r) {
                    const int k = khalf * 32 + ktl * 16 + lg * 4 + r;
                    *(unsigned short*)(PTp + k * TSTR + ((((n >> 3) ^ k) & 7) << 4) + (n & 7) * 2) =
                        f2bf(p[ktl][r] * scale);
                }
        }
        __syncthreads();

        // ---- softsum chunk-partial (thread: k = t>>3, chunk c = t&7)
        {
            const int kk = t >> 3;
            const int c  = t & 7;
            const short8 v = lds_read16(PTp + kk * TSTR + (((c ^ kk) & 7) << 4));
#pragma unroll
            for (int e = 0; e < 8; ++e) ss_acc += bf2f((unsigned short)v[e]);
        }

        // ---- agg MFMA: contraction n=64 (2 steps), A = XL rows d, B = PT rows k
#pragma unroll
        for (int kc = 0; kc < 2; ++kc) {
#pragma unroll
            for (int m = 0; m < 4; ++m) {
                const int d = w * 64 + m * 16 + lr;
                const int aC = kc * 4 + lg;
                const short8 afrag = lds_read16(XLp + d * TSTR + (((aC ^ d) & 7) << 4));
#pragma unroll
                for (int kt = 0; kt < 4; ++kt) {
                    const int k = kt * 16 + lr;
                    const short8 bfrag = lds_read16(PTp + k * TSTR + (((aC ^ k) & 7) << 4));
                    aacc[m][kt] = __builtin_amdgcn_mfma_f32_16x16x32_bf16(afrag, bfrag, aacc[m][kt], 0, 0, 0);
                }
            }
        }
        __syncthreads();   // XL/PT reads done before next tile restages
    }

    // ---- store agg partial: aggs[ns][b][d][k]
    float* ag = aggs + ((size_t)ns * B_ + b) * (D_ * K_);
#pragma unroll
    for (int m = 0; m < 4; ++m)
#pragma unroll
        for (int kt = 0; kt < 4; ++kt)
#pragma unroll
            for (int r = 0; r < 4; ++r)
                ag[(size_t)(w * 64 + m * 16 + lg * 4 + r) * K_ + kt * 16 + lr] = aacc[m][kt][r];

    // ---- store softsum partial: ssp[b][ns][k]
    ss_acc += __shfl_xor(ss_acc, 1);
    ss_acc += __shfl_xor(ss_acc, 2);
    ss_acc += __shfl_xor(ss_acc, 4);
    if ((t & 7) == 0) ssp[((size_t)b * 8 + ns) * K_ + (t >> 3)] = ss_acc;
}

// ---------------------------------------------------------------------------
// Kernel D1: vsum = sum_ns aggs - centers*softsum -> aggsum; partial sumsq -> nrmp
// ---------------------------------------------------------------------------
__global__ __launch_bounds__(256) void vlad_norm1(const float* __restrict__ aggs,
                                                  const float* __restrict__ centers,
                                                  const float* __restrict__ ssp,
                                                  float* __restrict__ aggsum,
                                                  float* __restrict__ nrmp) {
    const int ds = blockIdx.x;  // 0..7
    const int b  = blockIdx.y;
    const int t  = threadIdx.x;
    const int k  = t & 63;
    const int dg = t >> 6;

    __shared__ float red[4][64];

    float s0 = ssp[((size_t)b * 8 + dg) * K_ + k] + ssp[((size_t)b * 8 + dg + 4) * K_ + k];
    red[dg][k] = s0;
    __syncthreads();
    const float s = red[0][k] + red[1][k] + red[2][k] + red[3][k];
    __syncthreads();

    float sq = 0.f;
    for (int d = ds * 64 + dg; d < ds * 64 + 64; d += 4) {
        float v = -centers[d * K_ + k] * s;
#pragma unroll
        for (int i = 0; i < 8; ++i)
            v += aggs[((size_t)i * B_ + b) * (D_ * K_) + (size_t)d * K_ + k];
        aggsum[((size_t)b * D_ + d) * K_ + k] = v;
        sq = fmaf(v, v, sq);
    }
    red[dg][k] = sq;
    __syncthreads();
    if (t < 64) nrmp[((size_t)b * 8 + ds) * K_ + k] =
        red[0][k] + red[1][k] + red[2][k] + red[3][k];
}

// ---------------------------------------------------------------------------
// Kernel D2: finalize norms (intra-D + global L2), scale aggsum -> out
// ---------------------------------------------------------------------------
__global__ __launch_bounds__(256) void vlad_norm2(const float* __restrict__ aggsum,
                                                  const float* __restrict__ nrmp,
                                                  float* __restrict__ out) {
    const int ds = blockIdx.x;  // 0..7
    const int b  = blockIdx.y;
    const int t  = threadIdx.x;
    const int k  = t & 63;
    const int dg = t >> 6;

    __shared__ float inv1s[64];
    __shared__ float col2[64];
    __shared__ float inv2s;

    if (t < 64) {
        float tt = 0.f;
#pragma unroll
        for (int i = 0; i < 8; ++i) tt += nrmp[((size_t)b * 8 + i) * K_ + k];
        const float n1 = sqrtf(tt);
        const float i1 = 1.f / fmaxf(n1, 1e-12f);
        inv1s[k] = i1;
        const float c2 = n1 * i1;
        col2[k] = c2 * c2;
    }
    __syncthreads();
    if (t == 0) {
        float tt = 0.f;
        for (int kk = 0; kk < 64; ++kk) tt += col2[kk];
        inv2s = 1.f / fmaxf(sqrtf(tt), 1e-12f);
    }
    __syncthreads();
    const float i12 = inv1s[k] * inv2s;
    for (int d = ds * 64 + dg; d < ds * 64 + 64; d += 4)
        out[(size_t)b * (D_ * K_) + (size_t)d * K_ + k] =
            aggsum[((size_t)b * D_ + d) * K_ + k] * i12;
}

// ---------------------------------------------------------------------------
extern "C" void kernel_launch(void* const* d_in, const int* in_sizes, int n_in,
                              void* d_out, int out_size, void* d_ws, size_t ws_size,
                              hipStream_t stream) {
    const float* X       = (const float*)d_in[0];  // [B, D, N]
    const float* W       = (const float*)d_in[1];  // [K, D]
    const float* bias    = (const float*)d_in[2];  // [K]
    const float* centers = (const float*)d_in[3];  // [D, K]
    float* out = (float*)d_out;

    char* ws = (char*)d_ws;
    const size_t aggBytes = (size_t)B_ * D_ * K_ * sizeof(float);   // 4 MB
    float* aggs   = (float*)ws;                               // 8 x 4 MB
    float* aggsum = (float*)(ws + 8 * aggBytes);              // 4 MB
    float* ssp    = (float*)(ws + 9 * aggBytes);              // [B][8][K]
    float* nrmp   = (float*)(ws + 9 * aggBytes + 65536);      // [B][8][K]

    hipFuncSetAttribute((const void*)vlad_fused,
                        hipFuncAttributeMaxDynamicSharedMemorySize, SMEM_BYTES);

    vlad_fused<<<dim3(8, B_), 512, SMEM_BYTES, stream>>>(X, W, bias, aggs, ssp);
    vlad_norm1<<<dim3(8, B_), 256, 0, stream>>>(aggs, centers, ssp, aggsum, nrmp);
    vlad_norm2<<<dim3(8, B_), 256, 0, stream>>>(aggsum, nrmp, out);
}

// Round 11
// 83.804 us; speedup vs baseline: 9.8780x; 1.0196x over previous
//
#include <hip/hip_runtime.h>
#include <hip/hip_bf16.h>

#define B_ 32
#define D_ 512
#define K_ 64
#define N_ 4096

typedef __attribute__((ext_vector_type(8))) short short8;   // 8 bf16 (4 VGPRs)
typedef __attribute__((ext_vector_type(4))) short short4v;  // 4 bf16 (8 bytes)
typedef __attribute__((ext_vector_type(4))) float f32x4;

static __device__ __forceinline__ unsigned short f2bf(float f) {
    __hip_bfloat16 h = __float2bfloat16(f);
    return *reinterpret_cast<unsigned short*>(&h);
}
static __device__ __forceinline__ float bf2f(unsigned short u) {
    return __uint_as_float(((unsigned)u) << 16);
}

// LDS carve (bytes): WL 64K | XL 64K | XT 2x8K | PT 8K | sxc 1K
#define SMEM_BYTES 156672
#define WL_OFF 0
#define XL_OFF 65536
#define XT_OFF 131072
#define PT_OFF 147456
#define SXC_OFF 155648

// ---------------------------------------------------------------------------
// Fused kernel, pipe-diverse segments: per inter-barrier region {issue global
// load (VMEM) | f2bf+ds_write of stage s+1 (VALU+LDS-W) | ds_read+MFMA of
// stage s (LDS-R+MFMA)} so no pipe sits idle behind the barrier. XT staging
// swizzle fixed to C^(n&7)^((n>>3)&7): write lanes spread 8 chunk slots x 4
// byte lanes (was 8-way conflicted). Softsum accumulated in registers
// (bit-identical to PT re-read). X read from HBM exactly once.
// Block 512 thr (8 waves), 1 block/CU. Grid 8 ns x 32 b.
// ---------------------------------------------------------------------------
__global__ __launch_bounds__(512, 2) void vlad_fused(const float* __restrict__ X,
                                                     const float* __restrict__ W,
                                                     const float* __restrict__ bias,
                                                     float* __restrict__ aggs,
                                                     float* __restrict__ ssp) {
    extern __shared__ char smem[];
    char* WLp = smem + WL_OFF;
    char* XLp = smem + XL_OFF;
    char* XTp = smem + XT_OFF;
    char* PTp = smem + PT_OFF;
    float2* sxc = (float2*)(smem + SXC_OFF);   // [8 waves][16 lr] (c, sum)

    const int ns = blockIdx.x;   // 0..7  (n-range [ns*512, ns*512+512))
    const int b  = blockIdx.y;
    const int t  = threadIdx.x;
    const int w  = t >> 6;
    const int l  = t & 63;
    const int lg = l >> 4;
    const int lr = l & 15;
    const int strip = w & 3;
    const int khalf = w >> 2;

    // staging role: 2 d-rows x 4 n-cols per thread
    const int dq2 = t >> 4;   // 0..31 -> local d0 = dq2*2
    const int nq  = t & 15;   // n0 = nq*4
    const float* Xbase = X + (size_t)b * D_ * N_ + ns * 512 + nq * 4;

    // ---- prefetch slots: stages 0..3 of tile 0 (slot = stage&3, static idx)
    float4 Sa[4], Sb[4];
#pragma unroll
    for (int s = 0; s < 4; ++s) {
        const float* Xs = Xbase + (size_t)(s * 64 + dq2 * 2) * N_;
        Sa[s] = *(const float4*)&Xs[0];
        Sb[s] = *(const float4*)&Xs[N_];
    }

    // ---- stage full W -> WL [64 k][512 d] bf16, 1KB rows, XOR-swz (validated)
#pragma unroll 4
    for (int j = 0; j < 16; ++j) {
        const int idx = t + j * 512;       // f4 index over [64 k][128 f4]
        const int k = idx >> 7;
        const int cf = idx & 127;
        const float4 wv = *(const float4*)&W[k * D_ + cf * 4];
        const int C = cf >> 1;
        const int swz = (C & ~7) | ((C ^ k) & 7);
        short4v pk;
        pk[0] = (short)f2bf(wv.x); pk[1] = (short)f2bf(wv.y);
        pk[2] = (short)f2bf(wv.z); pk[3] = (short)f2bf(wv.w);
        *(short4v*)(WLp + k * 1024 + (swz << 4) + (cf & 1) * 8) = pk;
    }

    float bias_r[2][4];
#pragma unroll
    for (int ktl = 0; ktl < 2; ++ktl)
#pragma unroll
        for (int r = 0; r < 4; ++r)
            bias_r[ktl][r] = bias[khalf * 32 + ktl * 16 + lg * 4 + r];

    f32x4 aacc[4][4];
#pragma unroll
    for (int m = 0; m < 4; ++m)
#pragma unroll
        for (int kt = 0; kt < 4; ++kt) {
            aacc[m][kt][0] = 0.f; aacc[m][kt][1] = 0.f;
            aacc[m][kt][2] = 0.f; aacc[m][kt][3] = 0.f;
        }
    float ssr[2][4];   // in-register softsum partials (this lane's 8 k's)
#pragma unroll
    for (int ktl = 0; ktl < 2; ++ktl)
#pragma unroll
        for (int r = 0; r < 4; ++r) ssr[ktl][r] = 0.f;

    // write one staged 2x4 block into XL (row dglob0) + XT[buf] (transposed)
    auto stage_write = [&](int buf, int dglob0, const float4& r0, const float4& r1) {
        const float e0[4] = {r0.x, r0.y, r0.z, r0.w};
        const float e1[4] = {r1.x, r1.y, r1.z, r1.w};
        {
            short4v pk;
            pk[0] = (short)f2bf(e0[0]); pk[1] = (short)f2bf(e0[1]);
            pk[2] = (short)f2bf(e0[2]); pk[3] = (short)f2bf(e0[3]);
            const int d = dglob0;
            *(short4v*)(XLp + d * 128 + ((((nq >> 1) ^ d) & 7) << 4) + (nq & 1) * 8) = pk;
        }
        {
            short4v pk;
            pk[0] = (short)f2bf(e1[0]); pk[1] = (short)f2bf(e1[1]);
            pk[2] = (short)f2bf(e1[2]); pk[3] = (short)f2bf(e1[3]);
            const int d = dglob0 + 1;
            *(short4v*)(XLp + d * 128 + ((((nq >> 1) ^ d) & 7) << 4) + (nq & 1) * 8) = pk;
        }
        const int C = dq2 >> 2;
#pragma unroll
        for (int c = 0; c < 4; ++c) {
            const int n = nq * 4 + c;
            const int sw = (C ^ (n & 7) ^ ((n >> 3) & 7)) & 7;   // conflict-free swz
            const unsigned v = (unsigned)f2bf(e0[c]) | ((unsigned)f2bf(e1[c]) << 16);
            *(unsigned*)(XTp + buf * 8192 + n * 128 + (sw << 4) + (dq2 & 3) * 4) = v;
        }
    };

    __syncthreads();   // WL ready

    for (int nt = 0; nt < 8; ++nt) {
        const int base = nt * 8;

        // ---- tile prologue: write stage base (slot 0); refill slot0 <- base+4
        stage_write(0, 0 * 64 + dq2 * 2, Sa[0], Sb[0]);
        {
            const int s4 = base + 4;
            if (s4 < 64) {
                const int nt2 = s4 >> 3, d2 = s4 & 7;
                const float* Xs = Xbase + nt2 * 64 + (size_t)(d2 * 64 + dq2 * 2) * N_;
                Sa[0] = *(const float4*)&Xs[0];
                Sb[0] = *(const float4*)&Xs[N_];
            }
        }
        __syncthreads();

        f32x4 sacc[2];
#pragma unroll
        for (int ktl = 0; ktl < 2; ++ktl) {
            sacc[ktl][0] = 0.f; sacc[ktl][1] = 0.f; sacc[ktl][2] = 0.f; sacc[ktl][3] = 0.f;
        }

#pragma unroll
        for (int dsl = 0; dsl < 8; ++dsl) {
            const int cur = dsl & 1;
            if (dsl < 7) {
                // write NEXT stage into the other XT buf + its XL rows,
                // then refill that slot (loads stay in flight 4+ segments)
                const int slot = (dsl + 1) & 3;
                stage_write(cur ^ 1, (dsl + 1) * 64 + dq2 * 2, Sa[slot], Sb[slot]);
                const int s5 = base + dsl + 5;
                if (s5 < 64) {
                    const int nt2 = s5 >> 3, d2 = s5 & 7;
                    const float* Xs = Xbase + nt2 * 64 + (size_t)(d2 * 64 + dq2 * 2) * N_;
                    Sa[slot] = *(const float4*)&Xs[0];
                    Sb[slot] = *(const float4*)&Xs[N_];
                }
            }
            // MFMA scores stage dsl on XT buf[cur] (same inter-barrier region)
            const int n = strip * 16 + lr;
#pragma unroll
            for (int kc = 0; kc < 2; ++kc) {
                const int bC = kc * 4 + lg;
                const int sw = (bC ^ (n & 7) ^ ((n >> 3) & 7)) & 7;
                const short8 bfrag = *(const short8*)(XTp + cur * 8192 + n * 128 + (sw << 4));
#pragma unroll
                for (int ktl = 0; ktl < 2; ++ktl) {
                    const int k = khalf * 32 + ktl * 16 + lr;
                    const int aC = dsl * 8 + kc * 4 + lg;
                    const int swz = (aC & ~7) | ((aC ^ k) & 7);
                    const short8 afrag = *(const short8*)(WLp + k * 1024 + (swz << 4));
                    sacc[ktl] = __builtin_amdgcn_mfma_f32_16x16x32_bf16(afrag, bfrag, sacc[ktl], 0, 0, 0);
                }
            }
            if (dsl < 7) __syncthreads();
        }

        // ---- softmax over k: wave-local shift (exact), single (c,sum) exchange
        float p[2][4];
        float cw = -1e30f;
#pragma unroll
        for (int ktl = 0; ktl < 2; ++ktl)
#pragma unroll
            for (int r = 0; r < 4; ++r) {
                p[ktl][r] = sacc[ktl][r] + bias_r[ktl][r];
                cw = fmaxf(cw, p[ktl][r]);
            }
        cw = fmaxf(cw, __shfl_xor(cw, 16));
        cw = fmaxf(cw, __shfl_xor(cw, 32));
        float sum = 0.f;
#pragma unroll
        for (int ktl = 0; ktl < 2; ++ktl)
#pragma unroll
            for (int r = 0; r < 4; ++r) { p[ktl][r] = __expf(p[ktl][r] - cw); sum += p[ktl][r]; }
        sum += __shfl_xor(sum, 16);
        sum += __shfl_xor(sum, 32);
        if (l < 16) sxc[w * 16 + lr] = make_float2(cw, sum);
        __syncthreads();
        const float2 other = sxc[(w ^ 4) * 16 + lr];
        const float cstar = fmaxf(cw, other.x);
        const float e_own = __expf(cw - cstar);
        const float e_oth = __expf(other.x - cstar);
        const float scale = e_own / (sum * e_own + other.y * e_oth);

        // ---- P tile -> LDS [64 k][64 n] bf16 + in-register softsum partial
        {
            const int n = strip * 16 + lr;
#pragma unroll
            for (int ktl = 0; ktl < 2; ++ktl)
#pragma unroll
                for (int r = 0; r < 4; ++r) {
                    const int k = khalf * 32 + ktl * 16 + lg * 4 + r;
                    const unsigned short us = f2bf(p[ktl][r] * scale);
                    *(unsigned short*)(PTp + k * 128 + ((((n >> 3) ^ k) & 7) << 4) + (n & 7) * 2) = us;
                    ssr[ktl][r] += bf2f(us);   // bit-identical to the PT re-read
                }
        }
        __syncthreads();

        // ---- agg MFMA: contraction n=64 (2 steps); B-frags hoisted per kc
#pragma unroll
        for (int kc = 0; kc < 2; ++kc) {
            const int aC = kc * 4 + lg;
            short8 bfr[4];
#pragma unroll
            for (int kt = 0; kt < 4; ++kt) {
                const int kk2 = kt * 16 + lr;
                bfr[kt] = *(const short8*)(PTp + kk2 * 128 + (((aC ^ kk2) & 7) << 4));
            }
#pragma unroll
            for (int m = 0; m < 4; ++m) {
                const int d = w * 64 + m * 16 + lr;
                const short8 afrag = *(const short8*)(XLp + d * 128 + (((aC ^ d) & 7) << 4));
#pragma unroll
                for (int kt = 0; kt < 4; ++kt)
                    aacc[m][kt] = __builtin_amdgcn_mfma_f32_16x16x32_bf16(afrag, bfr[kt], aacc[m][kt], 0, 0, 0);
            }
        }
        __syncthreads();   // XL/PT reads done before next tile's prologue write
    }

    // ---- store agg partial: aggs[ns][b][d][k]
    float* ag = aggs + ((size_t)ns * B_ + b) * (D_ * K_);
#pragma unroll
    for (int m = 0; m < 4; ++m)
#pragma unroll
        for (int kt = 0; kt < 4; ++kt)
#pragma unroll
            for (int r = 0; r < 4; ++r)
                ag[(size_t)(w * 64 + m * 16 + lg * 4 + r) * K_ + kt * 16 + lr] = aacc[m][kt][r];

    // ---- softsum epilogue: butterfly over the 16-lane lr group, store partials
#pragma unroll
    for (int ktl = 0; ktl < 2; ++ktl)
#pragma unroll
        for (int r = 0; r < 4; ++r) {
            float v = ssr[ktl][r];
            v += __shfl_xor(v, 1);
            v += __shfl_xor(v, 2);
            v += __shfl_xor(v, 4);
            v += __shfl_xor(v, 8);
            ssr[ktl][r] = v;
        }
    if (lr == 0) {
#pragma unroll
        for (int ktl = 0; ktl < 2; ++ktl)
#pragma unroll
            for (int r = 0; r < 4; ++r) {
                const int k = khalf * 32 + ktl * 16 + lg * 4 + r;
                ssp[(((size_t)b * 8 + ns) * 4 + strip) * K_ + k] = ssr[ktl][r];
            }
    }
}

// ---------------------------------------------------------------------------
// Kernel D1: vsum = sum_ns aggs - centers*softsum -> aggsum; partial sumsq -> nrmp
// (ssp now [b][8 ns][4 strip][64 k] = 32 partials per (b,k))
// ---------------------------------------------------------------------------
__global__ __launch_bounds__(256) void vlad_norm1(const float* __restrict__ aggs,
                                                  const float* __restrict__ centers,
                                                  const float* __restrict__ ssp,
                                                  float* __restrict__ aggsum,
                                                  float* __restrict__ nrmp) {
    const int ds = blockIdx.x;  // 0..7
    const int b  = blockIdx.y;
    const int t  = threadIdx.x;
    const int k  = t & 63;
    const int dg = t >> 6;

    __shared__ float red[4][64];

    float s0 = 0.f;
#pragma unroll
    for (int j = 0; j < 8; ++j)
        s0 += ssp[((size_t)b * 32 + dg * 8 + j) * K_ + k];
    red[dg][k] = s0;
    __syncthreads();
    const float s = red[0][k] + red[1][k] + red[2][k] + red[3][k];
    __syncthreads();

    float sq = 0.f;
    for (int d = ds * 64 + dg; d < ds * 64 + 64; d += 4) {
        float v = -centers[d * K_ + k] * s;
#pragma unroll
        for (int i = 0; i < 8; ++i)
            v += aggs[((size_t)i * B_ + b) * (D_ * K_) + (size_t)d * K_ + k];
        aggsum[((size_t)b * D_ + d) * K_ + k] = v;
        sq = fmaf(v, v, sq);
    }
    red[dg][k] = sq;
    __syncthreads();
    if (t < 64) nrmp[((size_t)b * 8 + ds) * K_ + k] =
        red[0][k] + red[1][k] + red[2][k] + red[3][k];
}

// ---------------------------------------------------------------------------
// Kernel D2: finalize norms (intra-D + global L2), scale aggsum -> out
// ---------------------------------------------------------------------------
__global__ __launch_bounds__(256) void vlad_norm2(const float* __restrict__ aggsum,
                                                  const float* __restrict__ nrmp,
                                                  float* __restrict__ out) {
    const int ds = blockIdx.x;  // 0..7
    const int b  = blockIdx.y;
    const int t  = threadIdx.x;
    const int k  = t & 63;
    const int dg = t >> 6;

    __shared__ float inv1s[64];
    __shared__ float col2[64];
    __shared__ float inv2s;

    if (t < 64) {
        float tt = 0.f;
#pragma unroll
        for (int i = 0; i < 8; ++i) tt += nrmp[((size_t)b * 8 + i) * K_ + k];
        const float n1 = sqrtf(tt);
        const float i1 = 1.f / fmaxf(n1, 1e-12f);
        inv1s[k] = i1;
        const float c2 = n1 * i1;
        col2[k] = c2 * c2;
    }
    __syncthreads();
    if (t == 0) {
        float tt = 0.f;
        for (int kk = 0; kk < 64; ++kk) tt += col2[kk];
        inv2s = 1.f / fmaxf(sqrtf(tt), 1e-12f);
    }
    __syncthreads();
    const float i12 = inv1s[k] * inv2s;
    for (int d = ds * 64 + dg; d < ds * 64 + 64; d += 4)
        out[(size_t)b * (D_ * K_) + (size_t)d * K_ + k] =
            aggsum[((size_t)b * D_ + d) * K_ + k] * i12;
}

// ---------------------------------------------------------------------------
extern "C" void kernel_launch(void* const* d_in, const int* in_sizes, int n_in,
                              void* d_out, int out_size, void* d_ws, size_t ws_size,
                              hipStream_t stream) {
    const float* X       = (const float*)d_in[0];  // [B, D, N]
    const float* W       = (const float*)d_in[1];  // [K, D]
    const float* bias    = (const float*)d_in[2];  // [K]
    const float* centers = (const float*)d_in[3];  // [D, K]
    float* out = (float*)d_out;

    char* ws = (char*)d_ws;
    const size_t aggBytes = (size_t)B_ * D_ * K_ * sizeof(float);   // 4 MB
    float* aggs   = (float*)ws;                               // 8 x 4 MB
    float* aggsum = (float*)(ws + 8 * aggBytes);              // 4 MB
    float* ssp    = (float*)(ws + 9 * aggBytes);              // [B][8][4][K] = 256KB
    float* nrmp   = (float*)(ws + 9 * aggBytes + 262144);     // [B][8][K]

    hipFuncSetAttribute((const void*)vlad_fused,
                        hipFuncAttributeMaxDynamicSharedMemorySize, SMEM_BYTES);

    vlad_fused<<<dim3(8, B_), 512, SMEM_BYTES, stream>>>(X, W, bias, aggs, ssp);
    vlad_norm1<<<dim3(8, B_), 256, 0, stream>>>(aggs, centers, ssp, aggsum, nrmp);
    vlad_norm2<<<dim3(8, B_), 256, 0, stream>>>(aggsum, nrmp, out);
}